// Round 1
// baseline (318.795 us; speedup 1.0000x reference)
//
#include <hip/hip_runtime.h>

#define DI __device__ __forceinline__

typedef float        f32x4 __attribute__((ext_vector_type(4)));
typedef short        s16x8 __attribute__((ext_vector_type(8)));
typedef unsigned int u32x4 __attribute__((ext_vector_type(4)));
typedef unsigned int u32x2 __attribute__((ext_vector_type(2)));

// ---------- bf16 helpers (RNE) ----------
DI unsigned short f2bf(float f){
    unsigned u = __builtin_bit_cast(unsigned, f);
    u += 0x7fffu + ((u >> 16) & 1u);
    return (unsigned short)(u >> 16);
}
DI float bf2f(unsigned short h){
    unsigned u = ((unsigned)h) << 16;
    return __builtin_bit_cast(float, u);
}

// =====================================================================
// K1: tiled transpose + hi/lo bf16 split.  in[b][r][c] f32 -> oh/ol[b][c][r]
// =====================================================================
__global__ __launch_bounds__(256) void k_transpose_split(
    const float* __restrict__ in, unsigned short* __restrict__ oh,
    unsigned short* __restrict__ ol, int rows, int cols, long ibs, long obs)
{
    __shared__ float t[64][65];
    const int b  = blockIdx.z;
    const int r0 = blockIdx.y * 64, c0 = blockIdx.x * 64;
    const int tid = threadIdx.x;
    const float* ib = in + (long)b * ibs;

    #pragma unroll
    for (int i = 0; i < 4; ++i){
        int r  = (tid >> 4) + i * 16;
        int cq = (tid & 15) * 4;
        f32x4 v = *(const f32x4*)&ib[(long)(r0 + r) * cols + c0 + cq];
        t[r][cq+0] = v[0]; t[r][cq+1] = v[1]; t[r][cq+2] = v[2]; t[r][cq+3] = v[3];
    }
    __syncthreads();

    const int c  = tid >> 2;
    const int ms = (tid & 3) * 16;
    unsigned hv[8], lv[8];
    #pragma unroll
    for (int k2 = 0; k2 < 8; ++k2){
        float xa = t[ms + 2*k2 + 0][c];
        float xb = t[ms + 2*k2 + 1][c];
        unsigned short ha = f2bf(xa), la = f2bf(xa - bf2f(ha));
        unsigned short hb = f2bf(xb), lb = f2bf(xb - bf2f(hb));
        hv[k2] = (unsigned)ha | ((unsigned)hb << 16);
        lv[k2] = (unsigned)la | ((unsigned)lb << 16);
    }
    long o = (long)b * obs + (long)(c0 + c) * rows + r0 + ms;
    u32x4 H0 = {hv[0],hv[1],hv[2],hv[3]}, H1 = {hv[4],hv[5],hv[6],hv[7]};
    u32x4 L0 = {lv[0],lv[1],lv[2],lv[3]}, L1 = {lv[4],lv[5],lv[6],lv[7]};
    *(u32x4*)&oh[o]     = H0;  *(u32x4*)&oh[o + 8] = H1;
    *(u32x4*)&ol[o]     = L0;  *(u32x4*)&ol[o + 8] = L1;
}

// =====================================================================
// shared bt-GEMM core: C[i,j] += sum_k A[i,k]*B[j,k]  (split 3-pass)
// LDS tiles 128x64 bf16, XOR-swizzled (colb ^= (row&7)<<4)
// =====================================================================
DI void stage_tile(const unsigned short* __restrict__ src, long stride,
                   int row0, int k0, unsigned short* tile, int tid)
{
    #pragma unroll
    for (int it = 0; it < 4; ++it){
        int L    = (it * 256 + tid) * 16;           // logical byte offset
        int row  = L >> 7;
        int colb = L & 127;
        s16x8 v = *(const s16x8*)(src + (long)(row0 + row) * stride + k0 + (colb >> 1));
        int phys = (L & ~127) | (colb ^ ((row & 7) << 4));
        *(s16x8*)((char*)tile + phys) = v;
    }
}

DI s16x8 frag_ld(const unsigned short* tile, int row, int kc16)
{
    int logical = (row << 7) + (kc16 << 4);
    int phys    = logical ^ ((row & 7) << 4);
    return *(const s16x8*)((const char*)tile + phys);
}

DI void kloop(const unsigned short* ah, const unsigned short* al, int rowA0, long sA,
              const unsigned short* bh, const unsigned short* bl, int rowB0, long sB,
              int kbeg, int kend, f32x4 acc[4][4], unsigned short* lds, int tid)
{
    const int lane = tid & 63;
    const int wave = tid >> 6;
    const int wr = (wave >> 1) * 64, wc = (wave & 1) * 64;
    unsigned short* T0 = lds;
    unsigned short* T1 = lds + 8192;
    unsigned short* T2 = lds + 16384;
    unsigned short* T3 = lds + 24576;

    for (int k0 = kbeg; k0 < kend; k0 += 64){
        __syncthreads();
        stage_tile(ah, sA, rowA0, k0, T0, tid);
        stage_tile(al, sA, rowA0, k0, T1, tid);
        stage_tile(bh, sB, rowB0, k0, T2, tid);
        stage_tile(bl, sB, rowB0, k0, T3, tid);
        __syncthreads();

        #pragma unroll
        for (int ks = 0; ks < 2; ++ks){
            const int kc = ks * 4 + (lane >> 4);
            s16x8 bhf[4], blf[4];
            #pragma unroll
            for (int cf = 0; cf < 4; ++cf){
                int row = wc + cf * 16 + (lane & 15);
                bhf[cf] = frag_ld(T2, row, kc);
                blf[cf] = frag_ld(T3, row, kc);
            }
            #pragma unroll
            for (int rf = 0; rf < 4; ++rf){
                int row = wr + rf * 16 + (lane & 15);
                s16x8 ahf = frag_ld(T0, row, kc);
                s16x8 alf = frag_ld(T1, row, kc);
                #pragma unroll
                for (int cf = 0; cf < 4; ++cf){
                    acc[rf][cf] = __builtin_amdgcn_mfma_f32_16x16x32_bf16(ahf, bhf[cf], acc[rf][cf], 0, 0, 0);
                    acc[rf][cf] = __builtin_amdgcn_mfma_f32_16x16x32_bf16(ahf, blf[cf], acc[rf][cf], 0, 0, 0);
                    acc[rf][cf] = __builtin_amdgcn_mfma_f32_16x16x32_bf16(alf, bhf[cf], acc[rf][cf], 0, 0, 0);
                }
            }
        }
    }
}

// =====================================================================
// K2: Gram  G_b = X_b * X_b^T  (symmetric pairs i<=j, split-K=2)
// =====================================================================
__global__ __launch_bounds__(256) void k_gram(
    const unsigned short* __restrict__ Xh, const unsigned short* __restrict__ Xl,
    float* __restrict__ Gp)
{
    __shared__ unsigned short lds[4 * 8192];
    const int b = blockIdx.z, ksl = blockIdx.y;
    int ti = 0, tj = 0;
    { int q = blockIdx.x;
      #pragma unroll
      for (int i = 0; i < 6; ++i){ int c = 6 - i; if (q < c){ ti = i; tj = i + q; q = -1; break; } q -= c; } }

    const unsigned short* XH = Xh + (long)b * 768 * 4096;
    const unsigned short* XL = Xl + (long)b * 768 * 4096;

    f32x4 acc[4][4];
    #pragma unroll
    for (int i = 0; i < 4; ++i)
        #pragma unroll
        for (int j = 0; j < 4; ++j) acc[i][j] = (f32x4){0.f, 0.f, 0.f, 0.f};

    kloop(XH, XL, ti * 128, 4096, XH, XL, tj * 128, 4096,
          ksl * 2048, ksl * 2048 + 2048, acc, lds, threadIdx.x);

    float* G = Gp + ((long)ksl * 8 + b) * 768 * 768;
    const int lane = threadIdx.x & 63, wave = threadIdx.x >> 6;
    const int wr = (wave >> 1) * 64, wc = (wave & 1) * 64;
    #pragma unroll
    for (int rf = 0; rf < 4; ++rf)
        #pragma unroll
        for (int cf = 0; cf < 4; ++cf){
            int gi = ti * 128 + wr + rf * 16 + 4 * (lane >> 4);
            int gj = tj * 128 + wc + cf * 16 + (lane & 15);
            #pragma unroll
            for (int r = 0; r < 4; ++r){
                float v = acc[rf][cf][r];
                G[(long)(gi + r) * 768 + gj] = v;
                if (ti != tj) G[(long)gj * 768 + gi + r] = v;
            }
        }
}

// =====================================================================
// K3: G = Gp0 + Gp1, then hi/lo split to bf16
// =====================================================================
__global__ __launch_bounds__(256) void k_sumsplit(
    const float* __restrict__ g0, const float* __restrict__ g1,
    unsigned short* __restrict__ gh, unsigned short* __restrict__ gl)
{
    long i = ((long)blockIdx.x * 256 + threadIdx.x) * 4;
    f32x4 a = *(const f32x4*)(g0 + i);
    f32x4 b = *(const f32x4*)(g1 + i);
    unsigned hv[2], lv[2];
    #pragma unroll
    for (int k2 = 0; k2 < 2; ++k2){
        float va = a[2*k2+0] + b[2*k2+0];
        float vb = a[2*k2+1] + b[2*k2+1];
        unsigned short ha = f2bf(va), la = f2bf(va - bf2f(ha));
        unsigned short hb = f2bf(vb), lb = f2bf(vb - bf2f(hb));
        hv[k2] = (unsigned)ha | ((unsigned)hb << 16);
        lv[k2] = (unsigned)la | ((unsigned)lb << 16);
    }
    *(u32x2*)(gh + i) = (u32x2){hv[0], hv[1]};
    *(u32x2*)(gl + i) = (u32x2){lv[0], lv[1]};
}

// =====================================================================
// K4: TT_b[eg,c] = sum_c' WvT[eg,c'] * G_b[c,c']   (split in, split-bf16 out)
// =====================================================================
__global__ __launch_bounds__(256) void k_tt(
    const unsigned short* __restrict__ WTh, const unsigned short* __restrict__ WTl,
    const unsigned short* __restrict__ Gh,  const unsigned short* __restrict__ Gl,
    unsigned short* __restrict__ TTh, unsigned short* __restrict__ TTl)
{
    __shared__ unsigned short lds[4 * 8192];
    const int b = blockIdx.z;
    const int ti = blockIdx.x % 6, tj = blockIdx.x / 6;

    const unsigned short* AH = WTh + (long)768 * 768;   // WvT rows
    const unsigned short* AL = WTl + (long)768 * 768;
    const unsigned short* BH = Gh + (long)b * 768 * 768;
    const unsigned short* BL = Gl + (long)b * 768 * 768;

    f32x4 acc[4][4];
    #pragma unroll
    for (int i = 0; i < 4; ++i)
        #pragma unroll
        for (int j = 0; j < 4; ++j) acc[i][j] = (f32x4){0.f, 0.f, 0.f, 0.f};

    kloop(AH, AL, ti * 128, 768, BH, BL, tj * 128, 768, 0, 768, acc, lds, threadIdx.x);

    unsigned short* th = TTh + (long)b * 768 * 768;
    unsigned short* tl = TTl + (long)b * 768 * 768;
    const int lane = threadIdx.x & 63, wave = threadIdx.x >> 6;
    const int wr = (wave >> 1) * 64, wc = (wave & 1) * 64;
    #pragma unroll
    for (int rf = 0; rf < 4; ++rf)
        #pragma unroll
        for (int cf = 0; cf < 4; ++cf){
            int gi = ti * 128 + wr + rf * 16 + 4 * (lane >> 4);
            int gj = tj * 128 + wc + cf * 16 + (lane & 15);
            #pragma unroll
            for (int r = 0; r < 4; ++r){
                float v = acc[rf][cf][r];
                unsigned short h = f2bf(v);
                th[(long)(gi + r) * 768 + gj] = h;
                tl[(long)(gi + r) * 768 + gj] = f2bf(v - bf2f(h));
            }
        }
}

// =====================================================================
// K5: ctx_h = scale * WkT_h ·bt· TT_h  + softmax over d -> wT[e][d] bf16
// one wave per (b,h)
// =====================================================================
__global__ __launch_bounds__(64) void k_ctx(
    const unsigned short* __restrict__ WTh, const unsigned short* __restrict__ WTl,
    const unsigned short* __restrict__ TTh, const unsigned short* __restrict__ TTl,
    unsigned short* __restrict__ wT)
{
    const int bh = blockIdx.x;
    const int b = bh / 12, h = bh % 12;
    const int lane = threadIdx.x;

    const unsigned short* AH = WTh + (long)(h * 64) * 768;
    const unsigned short* AL = WTl + (long)(h * 64) * 768;
    const unsigned short* BH = TTh + (long)b * 768 * 768 + (long)(h * 64) * 768;
    const unsigned short* BL = TTl + (long)b * 768 * 768 + (long)(h * 64) * 768;

    f32x4 acc[4][4];
    #pragma unroll
    for (int i = 0; i < 4; ++i)
        #pragma unroll
        for (int j = 0; j < 4; ++j) acc[i][j] = (f32x4){0.f, 0.f, 0.f, 0.f};

    for (int kc = 0; kc < 24; ++kc){
        const int k0 = kc * 32 + (lane >> 4) * 8;
        s16x8 ahf[4], alf[4], bhf[4], blf[4];
        #pragma unroll
        for (int f = 0; f < 4; ++f){
            long ro = (long)(f * 16 + (lane & 15)) * 768 + k0;
            ahf[f] = *(const s16x8*)(AH + ro);
            alf[f] = *(const s16x8*)(AL + ro);
            bhf[f] = *(const s16x8*)(BH + ro);
            blf[f] = *(const s16x8*)(BL + ro);
        }
        #pragma unroll
        for (int rf = 0; rf < 4; ++rf)
            #pragma unroll
            for (int cf = 0; cf < 4; ++cf){
                acc[rf][cf] = __builtin_amdgcn_mfma_f32_16x16x32_bf16(ahf[rf], bhf[cf], acc[rf][cf], 0, 0, 0);
                acc[rf][cf] = __builtin_amdgcn_mfma_f32_16x16x32_bf16(ahf[rf], blf[cf], acc[rf][cf], 0, 0, 0);
                acc[rf][cf] = __builtin_amdgcn_mfma_f32_16x16x32_bf16(alf[rf], bhf[cf], acc[rf][cf], 0, 0, 0);
            }
    }

    // scale + softmax over d (rows); column e lives in lanes {e, e+16, e+32, e+48}
    unsigned short* wout = wT + (long)bh * 4096;
    #pragma unroll
    for (int cf = 0; cf < 4; ++cf){
        float pv[16];
        float m = -3.4e38f;
        #pragma unroll
        for (int rf = 0; rf < 4; ++rf)
            #pragma unroll
            for (int r = 0; r < 4; ++r){
                float s = acc[rf][cf][r] * 0.125f;
                pv[rf * 4 + r] = s;
                m = fmaxf(m, s);
            }
        m = fmaxf(m, __shfl_xor(m, 16));
        m = fmaxf(m, __shfl_xor(m, 32));
        float sum = 0.f;
        #pragma unroll
        for (int k = 0; k < 16; ++k){ pv[k] = __expf(pv[k] - m); sum += pv[k]; }
        sum += __shfl_xor(sum, 16);
        sum += __shfl_xor(sum, 32);
        float inv = 1.f / sum;
        int e = cf * 16 + (lane & 15);
        #pragma unroll
        for (int rf = 0; rf < 4; ++rf)
            #pragma unroll
            for (int r = 0; r < 4; ++r){
                int d = rf * 16 + 4 * (lane >> 4) + r;
                wout[e * 64 + d] = f2bf(pv[rf * 4 + r] * inv);
            }
    }
}

// =====================================================================
// K6: apply — o[src][b][n][h*64+e] = sum_d x[b][n][h*64+d] * w[b,h][e][d]
// =====================================================================
__global__ __launch_bounds__(256) void k_apply(
    const float* __restrict__ x1, const float* __restrict__ x2,
    const unsigned short* __restrict__ wT, float* __restrict__ out)
{
    __shared__ float ep[4][64][64];
    const int b = blockIdx.z;
    const int h = blockIdx.y >> 1;
    const int src = blockIdx.y & 1;
    const int lane = threadIdx.x & 63, wave = threadIdx.x >> 6;
    const int n0 = blockIdx.x * 256 + wave * 64;

    const float* x = (src ? x2 : x1) + (long)b * 4096 * 768;
    float* o = out + (long)src * 8 * 4096 * 768 + (long)b * 4096 * 768;

    const unsigned short* W = wT + (long)(b * 12 + h) * 4096;
    s16x8 bw[4][2];
    #pragma unroll
    for (int fe = 0; fe < 4; ++fe)
        #pragma unroll
        for (int ks = 0; ks < 2; ++ks)
            bw[fe][ks] = *(const s16x8*)(W + (fe * 16 + (lane & 15)) * 64 + ks * 32 + (lane >> 4) * 8);

    f32x4 acc[4][4];
    #pragma unroll
    for (int i = 0; i < 4; ++i)
        #pragma unroll
        for (int j = 0; j < 4; ++j) acc[i][j] = (f32x4){0.f, 0.f, 0.f, 0.f};

    #pragma unroll
    for (int rf = 0; rf < 4; ++rf){
        const int row = n0 + rf * 16 + (lane & 15);
        const float* xr = x + (long)row * 768 + h * 64 + (lane >> 4) * 8;
        f32x4 v0 = *(const f32x4*)(xr);
        f32x4 v1 = *(const f32x4*)(xr + 4);
        f32x4 v2 = *(const f32x4*)(xr + 32);
        f32x4 v3 = *(const f32x4*)(xr + 36);
        s16x8 a0, a1;
        #pragma unroll
        for (int t = 0; t < 4; ++t){
            a0[t]     = (short)f2bf(v0[t]);
            a0[t + 4] = (short)f2bf(v1[t]);
            a1[t]     = (short)f2bf(v2[t]);
            a1[t + 4] = (short)f2bf(v3[t]);
        }
        #pragma unroll
        for (int fe = 0; fe < 4; ++fe){
            acc[rf][fe] = __builtin_amdgcn_mfma_f32_16x16x32_bf16(a0, bw[fe][0], acc[rf][fe], 0, 0, 0);
            acc[rf][fe] = __builtin_amdgcn_mfma_f32_16x16x32_bf16(a1, bw[fe][1], acc[rf][fe], 0, 0, 0);
        }
    }

    // wave-local LDS restage for coalesced float4 stores
    #pragma unroll
    for (int rf = 0; rf < 4; ++rf)
        #pragma unroll
        for (int fe = 0; fe < 4; ++fe)
            #pragma unroll
            for (int r = 0; r < 4; ++r)
                ep[wave][rf * 16 + 4 * (lane >> 4) + r][fe * 16 + (lane & 15)] = acc[rf][fe][r];

    #pragma unroll
    for (int pass = 0; pass < 16; ++pass){
        int rr = pass * 4 + (lane >> 4);
        f32x4 v = *(const f32x4*)&ep[wave][rr][(lane & 15) * 4];
        *(f32x4*)&o[(long)(n0 + rr) * 768 + h * 64 + (lane & 15) * 4] = v;
    }
}

__global__ void k_sentinel(float* o){ o[0] = 1.0e9f; }

// =====================================================================
extern "C" void kernel_launch(void* const* d_in, const int* in_sizes, int n_in,
                              void* d_out, int out_size, void* d_ws, size_t ws_size,
                              hipStream_t stream)
{
    (void)in_sizes; (void)n_in; (void)out_size;
    const float* x1  = (const float*)d_in[0];
    const float* x2  = (const float*)d_in[1];
    const float* seg = (const float*)d_in[2];
    const float* Wkv = (const float*)d_in[3];

    size_t off = 0;
    auto alloc = [&](size_t bytes) -> void* {
        void* p = (char*)d_ws + off;
        off = (off + bytes + 255) & ~(size_t)255;
        return p;
    };
    unsigned short* Xh  = (unsigned short*)alloc((size_t)8 * 768 * 4096 * 2);
    unsigned short* Xl  = (unsigned short*)alloc((size_t)8 * 768 * 4096 * 2);
    unsigned short* WTh = (unsigned short*)alloc((size_t)1536 * 768 * 2);
    unsigned short* WTl = (unsigned short*)alloc((size_t)1536 * 768 * 2);
    float*          Gp  = (float*)alloc((size_t)2 * 8 * 768 * 768 * 4);
    unsigned short* Gh  = (unsigned short*)alloc((size_t)8 * 768 * 768 * 2);
    unsigned short* Gl  = (unsigned short*)alloc((size_t)8 * 768 * 768 * 2);
    unsigned short* TTh = (unsigned short*)alloc((size_t)8 * 768 * 768 * 2);
    unsigned short* TTl = (unsigned short*)alloc((size_t)8 * 768 * 768 * 2);
    unsigned short* wT  = (unsigned short*)alloc((size_t)96 * 64 * 64 * 2);

    if (ws_size < off){
        k_sentinel<<<1, 1, 0, stream>>>((float*)d_out);
        return;
    }

    // K1: seg -> X (split, transposed);  W_kv -> WT (split, transposed)
    k_transpose_split<<<dim3(12, 64, 8), 256, 0, stream>>>(
        seg, Xh, Xl, 4096, 768, (long)4096 * 768, (long)768 * 4096);
    k_transpose_split<<<dim3(24, 12, 1), 256, 0, stream>>>(
        Wkv, WTh, WTl, 768, 1536, 0, 0);

    // K2: Gram, symmetric pairs, split-K=2
    k_gram<<<dim3(21, 2, 8), 256, 0, stream>>>(Xh, Xl, Gp);

    // K3: combine split-K partials, split to bf16
    k_sumsplit<<<dim3((8 * 768 * 768) / (256 * 4)), 256, 0, stream>>>(
        Gp, Gp + (long)8 * 768 * 768, Gh, Gl);

    // K4: TT = WvT ·bt· G
    k_tt<<<dim3(36, 1, 8), 256, 0, stream>>>(WTh, WTl, Gh, Gl, TTh, TTl);

    // K5: ctx + softmax -> wT
    k_ctx<<<dim3(96), 64, 0, stream>>>(WTh, WTl, TTh, TTl, wT);

    // K6: apply to both queries
    k_apply<<<dim3(16, 24, 8), 256, 0, stream>>>(x1, x2, wT, (float*)d_out);
}

// Round 2
// 252.889 us; speedup vs baseline: 1.2606x; 1.2606x over previous
//
#include <hip/hip_runtime.h>

#define DI __device__ __forceinline__

typedef float        f32x4 __attribute__((ext_vector_type(4)));
typedef short        s16x8 __attribute__((ext_vector_type(8)));
typedef unsigned int u32x4 __attribute__((ext_vector_type(4)));
typedef unsigned int u32x2 __attribute__((ext_vector_type(2)));

// ---------- bf16 helpers (RNE) ----------
DI unsigned short f2bf(float f){
    unsigned u = __builtin_bit_cast(unsigned, f);
    u += 0x7fffu + ((u >> 16) & 1u);
    return (unsigned short)(u >> 16);
}
DI float bf2f(unsigned short h){
    unsigned u = ((unsigned)h) << 16;
    return __builtin_bit_cast(float, u);
}

// ---------- async global->LDS, 16B per lane ----------
DI void gl_lds16(const void* g, void* l){
    __builtin_amdgcn_global_load_lds(
        (const __attribute__((address_space(1))) unsigned int*)g,
        (__attribute__((address_space(3))) unsigned int*)l, 16, 0, 0);
}

// =====================================================================
// K1: tiled transpose + hi/lo bf16 split.  in[b][r][c] f32 -> oh/ol[b][c][r]
// =====================================================================
__global__ __launch_bounds__(256) void k_transpose_split(
    const float* __restrict__ in, unsigned short* __restrict__ oh,
    unsigned short* __restrict__ ol, int rows, int cols, long ibs, long obs)
{
    __shared__ float t[64][65];
    const int b  = blockIdx.z;
    const int r0 = blockIdx.y * 64, c0 = blockIdx.x * 64;
    const int tid = threadIdx.x;
    const float* ib = in + (long)b * ibs;

    #pragma unroll
    for (int i = 0; i < 4; ++i){
        int r  = (tid >> 4) + i * 16;
        int cq = (tid & 15) * 4;
        f32x4 v = *(const f32x4*)&ib[(long)(r0 + r) * cols + c0 + cq];
        t[r][cq+0] = v[0]; t[r][cq+1] = v[1]; t[r][cq+2] = v[2]; t[r][cq+3] = v[3];
    }
    __syncthreads();

    const int c  = tid >> 2;
    const int ms = (tid & 3) * 16;
    unsigned hv[8], lv[8];
    #pragma unroll
    for (int k2 = 0; k2 < 8; ++k2){
        float xa = t[ms + 2*k2 + 0][c];
        float xb = t[ms + 2*k2 + 1][c];
        unsigned short ha = f2bf(xa), la = f2bf(xa - bf2f(ha));
        unsigned short hb = f2bf(xb), lb = f2bf(xb - bf2f(hb));
        hv[k2] = (unsigned)ha | ((unsigned)hb << 16);
        lv[k2] = (unsigned)la | ((unsigned)lb << 16);
    }
    long o = (long)b * obs + (long)(c0 + c) * rows + r0 + ms;
    u32x4 H0 = {hv[0],hv[1],hv[2],hv[3]}, H1 = {hv[4],hv[5],hv[6],hv[7]};
    u32x4 L0 = {lv[0],lv[1],lv[2],lv[3]}, L1 = {lv[4],lv[5],lv[6],lv[7]};
    *(u32x4*)&oh[o]     = H0;  *(u32x4*)&oh[o + 8] = H1;
    *(u32x4*)&ol[o]     = L0;  *(u32x4*)&ol[o + 8] = L1;
}

// =====================================================================
// shared bt-GEMM core: C[i,j] += sum_k A[i,k]*B[j,k]  (hi/lo 3-pass)
// LDS tiles 128x64 bf16. gload_lds writes LINEAR dest; the XOR swizzle
// (colb ^= (row&7)<<4) is applied to the GLOBAL source address (involution),
// so frag_ld's swizzled read recovers the logical layout (rule #21/m173).
// =====================================================================
DI void stage_lds(const unsigned short* __restrict__ src, long stride,
                  int row0, int k0, unsigned short* tile, int tid)
{
    #pragma unroll
    for (int it = 0; it < 4; ++it){
        int D    = (it * 256 + tid) * 16;                 // dest byte (linear)
        int row  = D >> 7;
        int colb = (D & 127) ^ ((row & 7) << 4);          // inverse-swizzled source col
        const char* g = (const char*)(src + (long)(row0 + row) * stride + k0) + colb;
        gl_lds16(g, (char*)tile + D);
    }
}

DI s16x8 frag_ld(const unsigned short* tile, int row, int kc16)
{
    int logical = (row << 7) + (kc16 << 4);
    int phys    = logical ^ ((row & 7) << 4);
    return *(const s16x8*)((const char*)tile + phys);
}

DI void kloop(const unsigned short* ah, const unsigned short* al, int rowA0, long sA,
              const unsigned short* bh, const unsigned short* bl, int rowB0, long sB,
              int kbeg, int kend, f32x4 acc[4][4], unsigned short* lds, int tid)
{
    const int lane = tid & 63;
    const int wave = tid >> 6;
    const int wr = (wave >> 1) * 64, wc = (wave & 1) * 64;
    unsigned short* T0 = lds;
    unsigned short* T1 = lds + 8192;
    unsigned short* T2 = lds + 16384;
    unsigned short* T3 = lds + 24576;

    for (int k0 = kbeg; k0 < kend; k0 += 64){
        __syncthreads();
        stage_lds(ah, sA, rowA0, k0, T0, tid);
        stage_lds(al, sA, rowA0, k0, T1, tid);
        stage_lds(bh, sB, rowB0, k0, T2, tid);
        stage_lds(bl, sB, rowB0, k0, T3, tid);
        __syncthreads();   // compiler drains vmcnt(0) here

        #pragma unroll
        for (int ks = 0; ks < 2; ++ks){
            const int kc = ks * 4 + (lane >> 4);
            s16x8 bhf[4], blf[4];
            #pragma unroll
            for (int cf = 0; cf < 4; ++cf){
                int row = wc + cf * 16 + (lane & 15);
                bhf[cf] = frag_ld(T2, row, kc);
                blf[cf] = frag_ld(T3, row, kc);
            }
            #pragma unroll
            for (int rf = 0; rf < 4; ++rf){
                int row = wr + rf * 16 + (lane & 15);
                s16x8 ahf = frag_ld(T0, row, kc);
                s16x8 alf = frag_ld(T1, row, kc);
                #pragma unroll
                for (int cf = 0; cf < 4; ++cf){
                    acc[rf][cf] = __builtin_amdgcn_mfma_f32_16x16x32_bf16(ahf, bhf[cf], acc[rf][cf], 0, 0, 0);
                    acc[rf][cf] = __builtin_amdgcn_mfma_f32_16x16x32_bf16(ahf, blf[cf], acc[rf][cf], 0, 0, 0);
                    acc[rf][cf] = __builtin_amdgcn_mfma_f32_16x16x32_bf16(alf, bhf[cf], acc[rf][cf], 0, 0, 0);
                }
            }
        }
    }
}

// =====================================================================
// K2: Gram  G_b = X_b * X_b^T  (symmetric pairs i<=j, split-K=3)
// 1-D grid 504; b = id&7 so each XCD keeps one batch's panels L2-hot.
// =====================================================================
__global__ __launch_bounds__(256) void k_gram(
    const unsigned short* __restrict__ Xh, const unsigned short* __restrict__ Xl,
    float* __restrict__ Gp)
{
    __shared__ unsigned short lds[4 * 8192];
    const int id  = blockIdx.x;
    const int b   = id & 7;
    const int r   = id >> 3;          // 0..62
    const int ksl = r / 21;
    int q = r % 21;
    int ti = 0, tj = 0;
    #pragma unroll
    for (int i = 0; i < 6; ++i){ int c = 6 - i; if (q < c){ ti = i; tj = i + q; q = -1; break; } q -= c; }

    static const int kb[4] = {0, 1408, 2752, 4096};

    const unsigned short* XH = Xh + (long)b * 768 * 4096;
    const unsigned short* XL = Xl + (long)b * 768 * 4096;

    f32x4 acc[4][4];
    #pragma unroll
    for (int i = 0; i < 4; ++i)
        #pragma unroll
        for (int j = 0; j < 4; ++j) acc[i][j] = (f32x4){0.f, 0.f, 0.f, 0.f};

    kloop(XH, XL, ti * 128, 4096, XH, XL, tj * 128, 4096,
          kb[ksl], kb[ksl + 1], acc, lds, threadIdx.x);

    float* G = Gp + ((long)ksl * 8 + b) * 768 * 768;
    const int lane = threadIdx.x & 63, wave = threadIdx.x >> 6;
    const int wr = (wave >> 1) * 64, wc = (wave & 1) * 64;
    #pragma unroll
    for (int rf = 0; rf < 4; ++rf)
        #pragma unroll
        for (int cf = 0; cf < 4; ++cf){
            int gi = ti * 128 + wr + rf * 16 + 4 * (lane >> 4);
            int gj = tj * 128 + wc + cf * 16 + (lane & 15);
            #pragma unroll
            for (int r2 = 0; r2 < 4; ++r2){
                float v = acc[rf][cf][r2];
                G[(long)(gi + r2) * 768 + gj] = v;
                if (ti != tj) G[(long)gj * 768 + gi + r2] = v;
            }
        }
}

// =====================================================================
// K3: G = sum of 3 split-K partials, then hi/lo split to bf16
// =====================================================================
__global__ __launch_bounds__(256) void k_sumsplit(
    const float* __restrict__ gp,
    unsigned short* __restrict__ gh, unsigned short* __restrict__ gl)
{
    const long S = 4718592;  // 8*768*768
    long i = ((long)blockIdx.x * 256 + threadIdx.x) * 4;
    f32x4 a = *(const f32x4*)(gp + i);
    f32x4 b = *(const f32x4*)(gp + S + i);
    f32x4 c = *(const f32x4*)(gp + 2 * S + i);
    unsigned hv[2], lv[2];
    #pragma unroll
    for (int k2 = 0; k2 < 2; ++k2){
        float va = a[2*k2+0] + b[2*k2+0] + c[2*k2+0];
        float vb = a[2*k2+1] + b[2*k2+1] + c[2*k2+1];
        unsigned short ha = f2bf(va), la = f2bf(va - bf2f(ha));
        unsigned short hb = f2bf(vb), lb = f2bf(vb - bf2f(hb));
        hv[k2] = (unsigned)ha | ((unsigned)hb << 16);
        lv[k2] = (unsigned)la | ((unsigned)lb << 16);
    }
    *(u32x2*)(gh + i) = (u32x2){hv[0], hv[1]};
    *(u32x2*)(gl + i) = (u32x2){lv[0], lv[1]};
}

// =====================================================================
// K4: TT_b[eg,c] = sum_c' WvT[eg,c'] * G_b[c,c']   (split in, split-bf16 out)
// 1-D grid 288; b = id&7 keeps G_b (2.4 MB) L2-resident per XCD.
// =====================================================================
__global__ __launch_bounds__(256) void k_tt(
    const unsigned short* __restrict__ WTh, const unsigned short* __restrict__ WTl,
    const unsigned short* __restrict__ Gh,  const unsigned short* __restrict__ Gl,
    unsigned short* __restrict__ TTh, unsigned short* __restrict__ TTl)
{
    __shared__ unsigned short lds[4 * 8192];
    const int id = blockIdx.x;
    const int b  = id & 7;
    const int t  = id >> 3;
    const int ti = t % 6, tj = t / 6;

    const unsigned short* AH = WTh + (long)768 * 768;   // WvT rows
    const unsigned short* AL = WTl + (long)768 * 768;
    const unsigned short* BH = Gh + (long)b * 768 * 768;
    const unsigned short* BL = Gl + (long)b * 768 * 768;

    f32x4 acc[4][4];
    #pragma unroll
    for (int i = 0; i < 4; ++i)
        #pragma unroll
        for (int j = 0; j < 4; ++j) acc[i][j] = (f32x4){0.f, 0.f, 0.f, 0.f};

    kloop(AH, AL, ti * 128, 768, BH, BL, tj * 128, 768, 0, 768, acc, lds, threadIdx.x);

    unsigned short* th = TTh + (long)b * 768 * 768;
    unsigned short* tl = TTl + (long)b * 768 * 768;
    const int lane = threadIdx.x & 63, wave = threadIdx.x >> 6;
    const int wr = (wave >> 1) * 64, wc = (wave & 1) * 64;
    #pragma unroll
    for (int rf = 0; rf < 4; ++rf)
        #pragma unroll
        for (int cf = 0; cf < 4; ++cf){
            int gi = ti * 128 + wr + rf * 16 + 4 * (lane >> 4);
            int gj = tj * 128 + wc + cf * 16 + (lane & 15);
            #pragma unroll
            for (int r = 0; r < 4; ++r){
                float v = acc[rf][cf][r];
                unsigned short h = f2bf(v);
                th[(long)(gi + r) * 768 + gj] = h;
                tl[(long)(gi + r) * 768 + gj] = f2bf(v - bf2f(h));
            }
        }
}

// =====================================================================
// K5: ctx_h = scale * WkT_h ·bt· TT_h  + softmax over d -> wT[e][d] bf16
// 4 waves per (b,h): waves split K, LDS-reduce, wave 0 does softmax.
// =====================================================================
__global__ __launch_bounds__(256) void k_ctx(
    const unsigned short* __restrict__ WTh, const unsigned short* __restrict__ WTl,
    const unsigned short* __restrict__ TTh, const unsigned short* __restrict__ TTl,
    unsigned short* __restrict__ wT)
{
    __shared__ float red[3][64][65];   // pad 65: bank = (lane+idx)%32, conflict-free
    const int bh = blockIdx.x;
    const int b = bh / 12, h = bh % 12;
    const int lane = threadIdx.x & 63;
    const int wave = threadIdx.x >> 6;

    const unsigned short* AH = WTh + (long)(h * 64) * 768;
    const unsigned short* AL = WTl + (long)(h * 64) * 768;
    const unsigned short* BH = TTh + (long)b * 768 * 768 + (long)(h * 64) * 768;
    const unsigned short* BL = TTl + (long)b * 768 * 768 + (long)(h * 64) * 768;

    f32x4 acc[4][4];
    #pragma unroll
    for (int i = 0; i < 4; ++i)
        #pragma unroll
        for (int j = 0; j < 4; ++j) acc[i][j] = (f32x4){0.f, 0.f, 0.f, 0.f};

    for (int kc = wave * 6; kc < wave * 6 + 6; ++kc){
        const int k0 = kc * 32 + (lane >> 4) * 8;
        s16x8 ahf[4], alf[4], bhf[4], blf[4];
        #pragma unroll
        for (int f = 0; f < 4; ++f){
            long ro = (long)(f * 16 + (lane & 15)) * 768 + k0;
            ahf[f] = *(const s16x8*)(AH + ro);
            alf[f] = *(const s16x8*)(AL + ro);
            bhf[f] = *(const s16x8*)(BH + ro);
            blf[f] = *(const s16x8*)(BL + ro);
        }
        #pragma unroll
        for (int rf = 0; rf < 4; ++rf)
            #pragma unroll
            for (int cf = 0; cf < 4; ++cf){
                acc[rf][cf] = __builtin_amdgcn_mfma_f32_16x16x32_bf16(ahf[rf], bhf[cf], acc[rf][cf], 0, 0, 0);
                acc[rf][cf] = __builtin_amdgcn_mfma_f32_16x16x32_bf16(ahf[rf], blf[cf], acc[rf][cf], 0, 0, 0);
                acc[rf][cf] = __builtin_amdgcn_mfma_f32_16x16x32_bf16(alf[rf], bhf[cf], acc[rf][cf], 0, 0, 0);
            }
    }

    if (wave > 0){
        #pragma unroll
        for (int rf = 0; rf < 4; ++rf)
            #pragma unroll
            for (int cf = 0; cf < 4; ++cf)
                #pragma unroll
                for (int r = 0; r < 4; ++r)
                    red[wave - 1][lane][(rf * 4 + cf) * 4 + r] = acc[rf][cf][r];
    }
    __syncthreads();
    if (wave != 0) return;

    #pragma unroll
    for (int rf = 0; rf < 4; ++rf)
        #pragma unroll
        for (int cf = 0; cf < 4; ++cf)
            #pragma unroll
            for (int r = 0; r < 4; ++r){
                int idx = (rf * 4 + cf) * 4 + r;
                acc[rf][cf][r] += red[0][lane][idx] + red[1][lane][idx] + red[2][lane][idx];
            }

    // scale + softmax over d (rows); column e lives in lanes {e, e+16, e+32, e+48}
    unsigned short* wout = wT + (long)bh * 4096;
    #pragma unroll
    for (int cf = 0; cf < 4; ++cf){
        float pv[16];
        float m = -3.4e38f;
        #pragma unroll
        for (int rf = 0; rf < 4; ++rf)
            #pragma unroll
            for (int r = 0; r < 4; ++r){
                float s = acc[rf][cf][r] * 0.125f;
                pv[rf * 4 + r] = s;
                m = fmaxf(m, s);
            }
        m = fmaxf(m, __shfl_xor(m, 16));
        m = fmaxf(m, __shfl_xor(m, 32));
        float sum = 0.f;
        #pragma unroll
        for (int k = 0; k < 16; ++k){ pv[k] = __expf(pv[k] - m); sum += pv[k]; }
        sum += __shfl_xor(sum, 16);
        sum += __shfl_xor(sum, 32);
        float inv = 1.f / sum;
        int e = cf * 16 + (lane & 15);
        #pragma unroll
        for (int rf = 0; rf < 4; ++rf)
            #pragma unroll
            for (int r = 0; r < 4; ++r){
                int d = rf * 16 + 4 * (lane >> 4) + r;
                wout[e * 64 + d] = f2bf(pv[rf * 4 + r] * inv);
            }
    }
}

// =====================================================================
// K6: apply — o[src][b][n][h*64+e] = sum_d x[b][n][h*64+d] * w[b,h][e][d]
// =====================================================================
__global__ __launch_bounds__(256) void k_apply(
    const float* __restrict__ x1, const float* __restrict__ x2,
    const unsigned short* __restrict__ wT, float* __restrict__ out)
{
    __shared__ float ep[4][64][64];
    const int b = blockIdx.z;
    const int h = blockIdx.y >> 1;
    const int src = blockIdx.y & 1;
    const int lane = threadIdx.x & 63, wave = threadIdx.x >> 6;
    const int n0 = blockIdx.x * 256 + wave * 64;

    const float* x = (src ? x2 : x1) + (long)b * 4096 * 768;
    float* o = out + (long)src * 8 * 4096 * 768 + (long)b * 4096 * 768;

    const unsigned short* W = wT + (long)(b * 12 + h) * 4096;
    s16x8 bw[4][2];
    #pragma unroll
    for (int fe = 0; fe < 4; ++fe)
        #pragma unroll
        for (int ks = 0; ks < 2; ++ks)
            bw[fe][ks] = *(const s16x8*)(W + (fe * 16 + (lane & 15)) * 64 + ks * 32 + (lane >> 4) * 8);

    f32x4 acc[4][4];
    #pragma unroll
    for (int i = 0; i < 4; ++i)
        #pragma unroll
        for (int j = 0; j < 4; ++j) acc[i][j] = (f32x4){0.f, 0.f, 0.f, 0.f};

    #pragma unroll
    for (int rf = 0; rf < 4; ++rf){
        const int row = n0 + rf * 16 + (lane & 15);
        const float* xr = x + (long)row * 768 + h * 64 + (lane >> 4) * 8;
        f32x4 v0 = *(const f32x4*)(xr);
        f32x4 v1 = *(const f32x4*)(xr + 4);
        f32x4 v2 = *(const f32x4*)(xr + 32);
        f32x4 v3 = *(const f32x4*)(xr + 36);
        s16x8 a0, a1;
        #pragma unroll
        for (int t = 0; t < 4; ++t){
            a0[t]     = (short)f2bf(v0[t]);
            a0[t + 4] = (short)f2bf(v1[t]);
            a1[t]     = (short)f2bf(v2[t]);
            a1[t + 4] = (short)f2bf(v3[t]);
        }
        #pragma unroll
        for (int fe = 0; fe < 4; ++fe){
            acc[rf][fe] = __builtin_amdgcn_mfma_f32_16x16x32_bf16(a0, bw[fe][0], acc[rf][fe], 0, 0, 0);
            acc[rf][fe] = __builtin_amdgcn_mfma_f32_16x16x32_bf16(a1, bw[fe][1], acc[rf][fe], 0, 0, 0);
        }
    }

    // wave-local LDS restage for coalesced float4 stores
    #pragma unroll
    for (int rf = 0; rf < 4; ++rf)
        #pragma unroll
        for (int fe = 0; fe < 4; ++fe)
            #pragma unroll
            for (int r = 0; r < 4; ++r)
                ep[wave][rf * 16 + 4 * (lane >> 4) + r][fe * 16 + (lane & 15)] = acc[rf][fe][r];

    #pragma unroll
    for (int pass = 0; pass < 16; ++pass){
        int rr = pass * 4 + (lane >> 4);
        f32x4 v = *(const f32x4*)&ep[wave][rr][(lane & 15) * 4];
        *(f32x4*)&o[(long)(n0 + rr) * 768 + h * 64 + (lane & 15) * 4] = v;
    }
}

__global__ void k_sentinel(float* o){ o[0] = 1.0e9f; }

// =====================================================================
extern "C" void kernel_launch(void* const* d_in, const int* in_sizes, int n_in,
                              void* d_out, int out_size, void* d_ws, size_t ws_size,
                              hipStream_t stream)
{
    (void)in_sizes; (void)n_in; (void)out_size;
    const float* x1  = (const float*)d_in[0];
    const float* x2  = (const float*)d_in[1];
    const float* seg = (const float*)d_in[2];
    const float* Wkv = (const float*)d_in[3];

    // Workspace layout with aliasing (X region is dead after K2; G/TT live there).
    char* W = (char*)d_ws;
    unsigned short* Xh  = (unsigned short*)(W);                 // 50,331,648
    unsigned short* Xl  = (unsigned short*)(W + 50331648);      // 50,331,648
    unsigned short* Gh  = (unsigned short*)(W);                 // alias (post-K2)
    unsigned short* Gl  = (unsigned short*)(W + 9437184);
    unsigned short* TTh = (unsigned short*)(W + 18874368);
    unsigned short* TTl = (unsigned short*)(W + 28311552);
    unsigned short* WTh = (unsigned short*)(W + 100663296);     // 2,359,296
    unsigned short* WTl = (unsigned short*)(W + 103022592);     // 2,359,296
    float*          Gp  = (float*)(W + 105381888);              // 3 x 18,874,368
    unsigned short* wT  = (unsigned short*)(W + 162004992);     // 786,432
    const size_t need = 162791424;

    if (ws_size < need){
        k_sentinel<<<1, 1, 0, stream>>>((float*)d_out);
        return;
    }

    // K1: seg -> X (split, transposed);  W_kv -> WT (split, transposed)
    k_transpose_split<<<dim3(12, 64, 8), 256, 0, stream>>>(
        seg, Xh, Xl, 4096, 768, (long)4096 * 768, (long)768 * 4096);
    k_transpose_split<<<dim3(24, 12, 1), 256, 0, stream>>>(
        Wkv, WTh, WTl, 768, 1536, 0, 0);

    // K2: Gram, symmetric pairs, split-K=3, XCD-affine
    k_gram<<<dim3(504), 256, 0, stream>>>(Xh, Xl, Gp);

    // K3: combine split-K partials, split to bf16
    k_sumsplit<<<dim3(4608), 256, 0, stream>>>(Gp, Gh, Gl);

    // K4: TT = WvT ·bt· G
    k_tt<<<dim3(288), 256, 0, stream>>>(WTh, WTl, Gh, Gl, TTh, TTl);

    // K5: ctx + softmax -> wT
    k_ctx<<<dim3(96), 256, 0, stream>>>(WTh, WTl, TTh, TTl, wT);

    // K6: apply to both queries
    k_apply<<<dim3(16, 24, 8), 256, 0, stream>>>(x1, x2, wT, (float*)d_out);
}

// Round 3
// 200.203 us; speedup vs baseline: 1.5924x; 1.2632x over previous
//
#include <hip/hip_runtime.h>

#define DI __device__ __forceinline__

typedef float        f32x4 __attribute__((ext_vector_type(4)));
typedef _Float16     f16x8 __attribute__((ext_vector_type(8)));
typedef unsigned int u32x4 __attribute__((ext_vector_type(4)));
typedef unsigned int u32x2 __attribute__((ext_vector_type(2)));

DI unsigned short f2h(float f){
    _Float16 h = (_Float16)f;           // v_cvt_f16_f32, RNE
    return __builtin_bit_cast(unsigned short, h);
}

// ---------- async global->LDS, 16B per lane ----------
DI void gl_lds16(const void* g, void* l){
    __builtin_amdgcn_global_load_lds(
        (const __attribute__((address_space(1))) unsigned int*)g,
        (__attribute__((address_space(3))) unsigned int*)l, 16, 0, 0);
}

// =====================================================================
// K1: tiled transpose + f16 convert.  in[b][r][c] f32 -> o16[b][c][r] f16
// =====================================================================
__global__ __launch_bounds__(256) void k_transpose_f16(
    const float* __restrict__ in, unsigned short* __restrict__ o16,
    int rows, int cols, long ibs, long obs)
{
    __shared__ float t[64][65];
    const int b  = blockIdx.z;
    const int r0 = blockIdx.y * 64, c0 = blockIdx.x * 64;
    const int tid = threadIdx.x;
    const float* ib = in + (long)b * ibs;

    #pragma unroll
    for (int i = 0; i < 4; ++i){
        int r  = (tid >> 4) + i * 16;
        int cq = (tid & 15) * 4;
        f32x4 v = *(const f32x4*)&ib[(long)(r0 + r) * cols + c0 + cq];
        t[r][cq+0] = v[0]; t[r][cq+1] = v[1]; t[r][cq+2] = v[2]; t[r][cq+3] = v[3];
    }
    __syncthreads();

    const int c  = tid >> 2;
    const int ms = (tid & 3) * 16;
    unsigned hv[8];
    #pragma unroll
    for (int k2 = 0; k2 < 8; ++k2){
        unsigned short ha = f2h(t[ms + 2*k2 + 0][c]);
        unsigned short hb = f2h(t[ms + 2*k2 + 1][c]);
        hv[k2] = (unsigned)ha | ((unsigned)hb << 16);
    }
    long o = (long)b * obs + (long)(c0 + c) * rows + r0 + ms;
    u32x4 H0 = {hv[0],hv[1],hv[2],hv[3]}, H1 = {hv[4],hv[5],hv[6],hv[7]};
    *(u32x4*)&o16[o]     = H0;
    *(u32x4*)&o16[o + 8] = H1;
}

// =====================================================================
// shared bt-GEMM core (f16, single pass): C[i,j] += sum_k A[i,k]*B[j,k]
// LDS tiles 128x64 f16. gload_lds writes LINEAR dest; the XOR swizzle
// (colb ^= (row&7)<<4) is applied to the GLOBAL source address (involution),
// so frag_ld's swizzled read recovers the logical layout (rule #21/m173).
// =====================================================================
DI void stage_lds(const unsigned short* __restrict__ src, long stride,
                  int row0, int k0, unsigned short* tile, int tid)
{
    #pragma unroll
    for (int it = 0; it < 4; ++it){
        int D    = (it * 256 + tid) * 16;                 // dest byte (linear)
        int row  = D >> 7;
        int colb = (D & 127) ^ ((row & 7) << 4);          // inverse-swizzled source col
        const char* g = (const char*)(src + (long)(row0 + row) * stride + k0) + colb;
        gl_lds16(g, (char*)tile + D);
    }
}

DI f16x8 frag_ld(const unsigned short* tile, int row, int kc16)
{
    int logical = (row << 7) + (kc16 << 4);
    int phys    = logical ^ ((row & 7) << 4);
    return *(const f16x8*)((const char*)tile + phys);
}

DI void kloop(const unsigned short* a, int rowA0, long sA,
              const unsigned short* b, int rowB0, long sB,
              int kbeg, int kend, f32x4 acc[4][4], unsigned short* lds, int tid)
{
    const int lane = tid & 63;
    const int wave = tid >> 6;
    const int wr = (wave >> 1) * 64, wc = (wave & 1) * 64;
    unsigned short* TA = lds;
    unsigned short* TB = lds + 8192;

    for (int k0 = kbeg; k0 < kend; k0 += 64){
        __syncthreads();
        stage_lds(a, sA, rowA0, k0, TA, tid);
        stage_lds(b, sB, rowB0, k0, TB, tid);
        __syncthreads();   // compiler drains vmcnt(0) here

        #pragma unroll
        for (int ks = 0; ks < 2; ++ks){
            const int kc = ks * 4 + (lane >> 4);
            f16x8 bf[4];
            #pragma unroll
            for (int cf = 0; cf < 4; ++cf)
                bf[cf] = frag_ld(TB, wc + cf * 16 + (lane & 15), kc);
            #pragma unroll
            for (int rf = 0; rf < 4; ++rf){
                f16x8 af = frag_ld(TA, wr + rf * 16 + (lane & 15), kc);
                #pragma unroll
                for (int cf = 0; cf < 4; ++cf)
                    acc[rf][cf] = __builtin_amdgcn_mfma_f32_16x16x32_f16(af, bf[cf], acc[rf][cf], 0, 0, 0);
            }
        }
    }
}

// =====================================================================
// K2: Gram  G_b = X_b * X_b^T  (symmetric pairs i<=j, split-K=3)
// 1-D grid 504; b = id&7 so each XCD keeps one batch's panels L2-hot.
// =====================================================================
__global__ __launch_bounds__(256) void k_gram(
    const unsigned short* __restrict__ X, float* __restrict__ Gp)
{
    __shared__ unsigned short lds[2 * 8192];
    const int id  = blockIdx.x;
    const int b   = id & 7;
    const int r   = id >> 3;          // 0..62
    const int ksl = r / 21;
    int q = r % 21;
    int ti = 0, tj = 0;
    #pragma unroll
    for (int i = 0; i < 6; ++i){ int c = 6 - i; if (q < c){ ti = i; tj = i + q; q = -1; break; } q -= c; }

    static const int kb[4] = {0, 1408, 2752, 4096};

    const unsigned short* XB = X + (long)b * 768 * 4096;

    f32x4 acc[4][4];
    #pragma unroll
    for (int i = 0; i < 4; ++i)
        #pragma unroll
        for (int j = 0; j < 4; ++j) acc[i][j] = (f32x4){0.f, 0.f, 0.f, 0.f};

    kloop(XB, ti * 128, 4096, XB, tj * 128, 4096,
          kb[ksl], kb[ksl + 1], acc, lds, threadIdx.x);

    float* G = Gp + ((long)ksl * 8 + b) * 768 * 768;
    const int lane = threadIdx.x & 63, wave = threadIdx.x >> 6;
    const int wr = (wave >> 1) * 64, wc = (wave & 1) * 64;
    #pragma unroll
    for (int rf = 0; rf < 4; ++rf)
        #pragma unroll
        for (int cf = 0; cf < 4; ++cf){
            int gi = ti * 128 + wr + rf * 16 + 4 * (lane >> 4);
            int gj = tj * 128 + wc + cf * 16 + (lane & 15);
            #pragma unroll
            for (int r2 = 0; r2 < 4; ++r2){
                float v = acc[rf][cf][r2];
                G[(long)(gi + r2) * 768 + gj] = v;
                if (ti != tj) G[(long)gj * 768 + gi + r2] = v;
            }
        }
}

// =====================================================================
// K3: G = sum of 3 split-K partials -> f16
// =====================================================================
__global__ __launch_bounds__(256) void k_sumsplit(
    const float* __restrict__ gp, unsigned short* __restrict__ g16)
{
    const long S = 4718592;  // 8*768*768
    long i = ((long)blockIdx.x * 256 + threadIdx.x) * 4;
    f32x4 a = *(const f32x4*)(gp + i);
    f32x4 b = *(const f32x4*)(gp + S + i);
    f32x4 c = *(const f32x4*)(gp + 2 * S + i);
    unsigned hv[2];
    #pragma unroll
    for (int k2 = 0; k2 < 2; ++k2){
        unsigned short ha = f2h(a[2*k2+0] + b[2*k2+0] + c[2*k2+0]);
        unsigned short hb = f2h(a[2*k2+1] + b[2*k2+1] + c[2*k2+1]);
        hv[k2] = (unsigned)ha | ((unsigned)hb << 16);
    }
    *(u32x2*)(g16 + i) = (u32x2){hv[0], hv[1]};
}

// =====================================================================
// K4: TT_b[eg,c] = sum_c' WvT[eg,c'] * G_b[c,c']
// 1-D grid 288; b = id&7 keeps G_b (1.2 MB) L2-resident per XCD.
// =====================================================================
__global__ __launch_bounds__(256) void k_tt(
    const unsigned short* __restrict__ WT, const unsigned short* __restrict__ G,
    unsigned short* __restrict__ TT)
{
    __shared__ unsigned short lds[2 * 8192];
    const int id = blockIdx.x;
    const int b  = id & 7;
    const int t  = id >> 3;
    const int ti = t % 6, tj = t / 6;

    const unsigned short* A = WT + (long)768 * 768;   // WvT rows
    const unsigned short* B = G + (long)b * 768 * 768;

    f32x4 acc[4][4];
    #pragma unroll
    for (int i = 0; i < 4; ++i)
        #pragma unroll
        for (int j = 0; j < 4; ++j) acc[i][j] = (f32x4){0.f, 0.f, 0.f, 0.f};

    kloop(A, ti * 128, 768, B, tj * 128, 768, 0, 768, acc, lds, threadIdx.x);

    unsigned short* tt = TT + (long)b * 768 * 768;
    const int lane = threadIdx.x & 63, wave = threadIdx.x >> 6;
    const int wr = (wave >> 1) * 64, wc = (wave & 1) * 64;
    #pragma unroll
    for (int rf = 0; rf < 4; ++rf)
        #pragma unroll
        for (int cf = 0; cf < 4; ++cf){
            int gi = ti * 128 + wr + rf * 16 + 4 * (lane >> 4);
            int gj = tj * 128 + wc + cf * 16 + (lane & 15);
            #pragma unroll
            for (int r = 0; r < 4; ++r)
                tt[(long)(gi + r) * 768 + gj] = f2h(acc[rf][cf][r]);
        }
}

// =====================================================================
// K5: ctx_h = scale * WkT_h ·bt· TT_h  + softmax over d -> wT[e][d] f16
// 4 waves per (b,h): waves split K, LDS-reduce, wave 0 does softmax.
// =====================================================================
__global__ __launch_bounds__(256) void k_ctx(
    const unsigned short* __restrict__ WT, const unsigned short* __restrict__ TT,
    unsigned short* __restrict__ wT)
{
    __shared__ float red[3][64][65];
    const int bh = blockIdx.x;
    const int b = bh / 12, h = bh % 12;
    const int lane = threadIdx.x & 63;
    const int wave = threadIdx.x >> 6;

    const unsigned short* A = WT + (long)(h * 64) * 768;
    const unsigned short* B = TT + (long)b * 768 * 768 + (long)(h * 64) * 768;

    f32x4 acc[4][4];
    #pragma unroll
    for (int i = 0; i < 4; ++i)
        #pragma unroll
        for (int j = 0; j < 4; ++j) acc[i][j] = (f32x4){0.f, 0.f, 0.f, 0.f};

    for (int kc = wave * 6; kc < wave * 6 + 6; ++kc){
        const int k0 = kc * 32 + (lane >> 4) * 8;
        f16x8 af[4], bf[4];
        #pragma unroll
        for (int f = 0; f < 4; ++f){
            long ro = (long)(f * 16 + (lane & 15)) * 768 + k0;
            af[f] = *(const f16x8*)(A + ro);
            bf[f] = *(const f16x8*)(B + ro);
        }
        #pragma unroll
        for (int rf = 0; rf < 4; ++rf)
            #pragma unroll
            for (int cf = 0; cf < 4; ++cf)
                acc[rf][cf] = __builtin_amdgcn_mfma_f32_16x16x32_f16(af[rf], bf[cf], acc[rf][cf], 0, 0, 0);
    }

    if (wave > 0){
        #pragma unroll
        for (int rf = 0; rf < 4; ++rf)
            #pragma unroll
            for (int cf = 0; cf < 4; ++cf)
                #pragma unroll
                for (int r = 0; r < 4; ++r)
                    red[wave - 1][lane][(rf * 4 + cf) * 4 + r] = acc[rf][cf][r];
    }
    __syncthreads();
    if (wave != 0) return;

    #pragma unroll
    for (int rf = 0; rf < 4; ++rf)
        #pragma unroll
        for (int cf = 0; cf < 4; ++cf)
            #pragma unroll
            for (int r = 0; r < 4; ++r){
                int idx = (rf * 4 + cf) * 4 + r;
                acc[rf][cf][r] += red[0][lane][idx] + red[1][lane][idx] + red[2][lane][idx];
            }

    // scale + softmax over d (rows); column e lives in lanes {e, e+16, e+32, e+48}
    unsigned short* wout = wT + (long)bh * 4096;
    #pragma unroll
    for (int cf = 0; cf < 4; ++cf){
        float pv[16];
        float m = -3.4e38f;
        #pragma unroll
        for (int rf = 0; rf < 4; ++rf)
            #pragma unroll
            for (int r = 0; r < 4; ++r){
                float s = acc[rf][cf][r] * 0.125f;
                pv[rf * 4 + r] = s;
                m = fmaxf(m, s);
            }
        m = fmaxf(m, __shfl_xor(m, 16));
        m = fmaxf(m, __shfl_xor(m, 32));
        float sum = 0.f;
        #pragma unroll
        for (int k = 0; k < 16; ++k){ pv[k] = __expf(pv[k] - m); sum += pv[k]; }
        sum += __shfl_xor(sum, 16);
        sum += __shfl_xor(sum, 32);
        float inv = 1.f / sum;
        int e = cf * 16 + (lane & 15);
        #pragma unroll
        for (int rf = 0; rf < 4; ++rf)
            #pragma unroll
            for (int r = 0; r < 4; ++r){
                int d = rf * 16 + 4 * (lane >> 4) + r;
                wout[e * 64 + d] = f2h(pv[rf * 4 + r] * inv);
            }
    }
}

// =====================================================================
// K6: apply — o[src][b][n][h*64+e] = sum_d x[b][n][h*64+d] * w[b,h][e][d]
// =====================================================================
__global__ __launch_bounds__(256) void k_apply(
    const float* __restrict__ x1, const float* __restrict__ x2,
    const unsigned short* __restrict__ wT, float* __restrict__ out)
{
    __shared__ float ep[4][64][64];
    const int b = blockIdx.z;
    const int h = blockIdx.y >> 1;
    const int src = blockIdx.y & 1;
    const int lane = threadIdx.x & 63, wave = threadIdx.x >> 6;
    const int n0 = blockIdx.x * 256 + wave * 64;

    const float* x = (src ? x2 : x1) + (long)b * 4096 * 768;
    float* o = out + (long)src * 8 * 4096 * 768 + (long)b * 4096 * 768;

    const unsigned short* W = wT + (long)(b * 12 + h) * 4096;
    f16x8 bw[4][2];
    #pragma unroll
    for (int fe = 0; fe < 4; ++fe)
        #pragma unroll
        for (int ks = 0; ks < 2; ++ks)
            bw[fe][ks] = *(const f16x8*)(W + (fe * 16 + (lane & 15)) * 64 + ks * 32 + (lane >> 4) * 8);

    f32x4 acc[4][4];
    #pragma unroll
    for (int i = 0; i < 4; ++i)
        #pragma unroll
        for (int j = 0; j < 4; ++j) acc[i][j] = (f32x4){0.f, 0.f, 0.f, 0.f};

    #pragma unroll
    for (int rf = 0; rf < 4; ++rf){
        const int row = n0 + rf * 16 + (lane & 15);
        const float* xr = x + (long)row * 768 + h * 64 + (lane >> 4) * 8;
        f32x4 v0 = *(const f32x4*)(xr);
        f32x4 v1 = *(const f32x4*)(xr + 4);
        f32x4 v2 = *(const f32x4*)(xr + 32);
        f32x4 v3 = *(const f32x4*)(xr + 36);
        f16x8 a0, a1;
        #pragma unroll
        for (int t = 0; t < 4; ++t){
            a0[t]     = (_Float16)v0[t];
            a0[t + 4] = (_Float16)v1[t];
            a1[t]     = (_Float16)v2[t];
            a1[t + 4] = (_Float16)v3[t];
        }
        #pragma unroll
        for (int fe = 0; fe < 4; ++fe){
            acc[rf][fe] = __builtin_amdgcn_mfma_f32_16x16x32_f16(a0, bw[fe][0], acc[rf][fe], 0, 0, 0);
            acc[rf][fe] = __builtin_amdgcn_mfma_f32_16x16x32_f16(a1, bw[fe][1], acc[rf][fe], 0, 0, 0);
        }
    }

    // wave-local LDS restage for coalesced float4 stores
    #pragma unroll
    for (int rf = 0; rf < 4; ++rf)
        #pragma unroll
        for (int fe = 0; fe < 4; ++fe)
            #pragma unroll
            for (int r = 0; r < 4; ++r)
                ep[wave][rf * 16 + 4 * (lane >> 4) + r][fe * 16 + (lane & 15)] = acc[rf][fe][r];

    #pragma unroll
    for (int pass = 0; pass < 16; ++pass){
        int rr = pass * 4 + (lane >> 4);
        f32x4 v = *(const f32x4*)&ep[wave][rr][(lane & 15) * 4];
        *(f32x4*)&o[(long)(n0 + rr) * 768 + h * 64 + (lane & 15) * 4] = v;
    }
}

__global__ void k_sentinel(float* o){ o[0] = 1.0e9f; }

// =====================================================================
extern "C" void kernel_launch(void* const* d_in, const int* in_sizes, int n_in,
                              void* d_out, int out_size, void* d_ws, size_t ws_size,
                              hipStream_t stream)
{
    (void)in_sizes; (void)n_in; (void)out_size;
    const float* x1  = (const float*)d_in[0];
    const float* x2  = (const float*)d_in[1];
    const float* seg = (const float*)d_in[2];
    const float* Wkv = (const float*)d_in[3];

    char* Wb = (char*)d_ws;
    unsigned short* X   = (unsigned short*)(Wb);                 // 50,331,648
    unsigned short* WT  = (unsigned short*)(Wb + 50331648);      //  2,359,296
    unsigned short* G   = (unsigned short*)(Wb + 52690944);      //  9,437,184
    unsigned short* TT  = (unsigned short*)(Wb + 62128128);      //  9,437,184
    unsigned short* wT  = (unsigned short*)(Wb + 71565312);      //    786,432
    float*          Gp  = (float*)(Wb + 72351744);               // 56,623,104
    const size_t need = 128974848;

    if (ws_size < need){
        k_sentinel<<<1, 1, 0, stream>>>((float*)d_out);
        return;
    }

    // K1: seg -> X (f16, transposed);  W_kv -> WT (f16, transposed)
    k_transpose_f16<<<dim3(12, 64, 8), 256, 0, stream>>>(
        seg, X, 4096, 768, (long)4096 * 768, (long)768 * 4096);
    k_transpose_f16<<<dim3(24, 12, 1), 256, 0, stream>>>(
        Wkv, WT, 768, 1536, 0, 0);

    // K2: Gram, symmetric pairs, split-K=3, XCD-affine
    k_gram<<<dim3(504), 256, 0, stream>>>(X, Gp);

    // K3: combine split-K partials -> f16
    k_sumsplit<<<dim3(4608), 256, 0, stream>>>(Gp, G);

    // K4: TT = WvT ·bt· G
    k_tt<<<dim3(288), 256, 0, stream>>>(WT, G, TT);

    // K5: ctx + softmax -> wT
    k_ctx<<<dim3(96), 256, 0, stream>>>(WT, TT, wT);

    // K6: apply to both queries
    k_apply<<<dim3(16, 24, 8), 256, 0, stream>>>(x1, x2, wT, (float*)d_out);
}

// Round 4
// 193.025 us; speedup vs baseline: 1.6516x; 1.0372x over previous
//
#include <hip/hip_runtime.h>

#define DI __device__ __forceinline__

typedef float        f32x4 __attribute__((ext_vector_type(4)));
typedef _Float16     f16x8 __attribute__((ext_vector_type(8)));
typedef unsigned int u32x4 __attribute__((ext_vector_type(4)));
typedef unsigned int u32x2 __attribute__((ext_vector_type(2)));

DI unsigned short f2h(float f){
    _Float16 h = (_Float16)f;           // v_cvt_f16_f32, RNE
    return __builtin_bit_cast(unsigned short, h);
}

// ---------- async global->LDS, 16B per lane ----------
DI void gl_lds16(const void* g, void* l){
    __builtin_amdgcn_global_load_lds(
        (const __attribute__((address_space(1))) unsigned int*)g,
        (__attribute__((address_space(3))) unsigned int*)l, 16, 0, 0);
}

// =====================================================================
// K1: tiled transpose + f16 convert.  in[b][r][c] f32 -> o16[b][c][r] f16
// =====================================================================
__global__ __launch_bounds__(256) void k_transpose_f16(
    const float* __restrict__ in, unsigned short* __restrict__ o16,
    int rows, int cols, long ibs, long obs)
{
    __shared__ float t[64][65];
    const int b  = blockIdx.z;
    const int r0 = blockIdx.y * 64, c0 = blockIdx.x * 64;
    const int tid = threadIdx.x;
    const float* ib = in + (long)b * ibs;

    #pragma unroll
    for (int i = 0; i < 4; ++i){
        int r  = (tid >> 4) + i * 16;
        int cq = (tid & 15) * 4;
        f32x4 v = *(const f32x4*)&ib[(long)(r0 + r) * cols + c0 + cq];
        t[r][cq+0] = v[0]; t[r][cq+1] = v[1]; t[r][cq+2] = v[2]; t[r][cq+3] = v[3];
    }
    __syncthreads();

    const int c  = tid >> 2;
    const int ms = (tid & 3) * 16;
    unsigned hv[8];
    #pragma unroll
    for (int k2 = 0; k2 < 8; ++k2){
        unsigned short ha = f2h(t[ms + 2*k2 + 0][c]);
        unsigned short hb = f2h(t[ms + 2*k2 + 1][c]);
        hv[k2] = (unsigned)ha | ((unsigned)hb << 16);
    }
    long o = (long)b * obs + (long)(c0 + c) * rows + r0 + ms;
    u32x4 H0 = {hv[0],hv[1],hv[2],hv[3]}, H1 = {hv[4],hv[5],hv[6],hv[7]};
    *(u32x4*)&o16[o]     = H0;
    *(u32x4*)&o16[o + 8] = H1;
}

// =====================================================================
// shared bt-GEMM core (f16): C[i,j] += sum_k A[i,k]*B[j,k]
// LDS tiles 128x64 f16, DOUBLE-BUFFERED (T3 minimal 2-phase prefetch):
//   prologue: stage buf0; sync
//   iter:     issue stage buf^1 (next K) ; compute buf ; sync ; flip
// __syncthreads' implicit vmcnt(0)+lgkmcnt(0) drain is the correctness fence:
// next-tile DMA lands under the MFMA phase, ds_reads drain before overwrite.
// gload_lds writes LINEAR dest; XOR swizzle (colb ^= (row&7)<<4) is applied
// to the GLOBAL source address (involution), frag_ld reads swizzled (m173).
// =====================================================================
DI void stage_lds(const unsigned short* __restrict__ src, long stride,
                  int row0, int k0, unsigned short* tile, int tid)
{
    #pragma unroll
    for (int it = 0; it < 4; ++it){
        int D    = (it * 256 + tid) * 16;                 // dest byte (linear)
        int row  = D >> 7;
        int colb = (D & 127) ^ ((row & 7) << 4);          // inverse-swizzled source col
        const char* g = (const char*)(src + (long)(row0 + row) * stride + k0) + colb;
        gl_lds16(g, (char*)tile + D);
    }
}

DI f16x8 frag_ld(const unsigned short* tile, int row, int kc16)
{
    int logical = (row << 7) + (kc16 << 4);
    int phys    = logical ^ ((row & 7) << 4);
    return *(const f16x8*)((const char*)tile + phys);
}

DI void kloop(const unsigned short* a, int rowA0, long sA,
              const unsigned short* b, int rowB0, long sB,
              int kbeg, int kend, f32x4 acc[4][4], unsigned short* lds, int tid)
{
    const int lane = tid & 63;
    const int wave = tid >> 6;
    const int wr = (wave >> 1) * 64, wc = (wave & 1) * 64;

    // prologue: stage first K-tile into buffer 0
    stage_lds(a, sA, rowA0, kbeg, lds,        tid);
    stage_lds(b, sB, rowB0, kbeg, lds + 8192, tid);
    __syncthreads();

    int cur = 0;
    for (int k0 = kbeg; k0 < kend; k0 += 64){
        const unsigned short* TA = lds + cur * 16384;
        const unsigned short* TB = TA + 8192;

        // issue next-tile loads (they fly under the MFMA phase below)
        const int kn = k0 + 64;
        if (kn < kend){
            unsigned short* NA = lds + (cur ^ 1) * 16384;
            stage_lds(a, sA, rowA0, kn, NA,        tid);
            stage_lds(b, sB, rowB0, kn, NA + 8192, tid);
        }

        #pragma unroll
        for (int ks = 0; ks < 2; ++ks){
            const int kc = ks * 4 + (lane >> 4);
            f16x8 bf[4];
            #pragma unroll
            for (int cf = 0; cf < 4; ++cf)
                bf[cf] = frag_ld(TB, wc + cf * 16 + (lane & 15), kc);
            #pragma unroll
            for (int rf = 0; rf < 4; ++rf){
                f16x8 af = frag_ld(TA, wr + rf * 16 + (lane & 15), kc);
                #pragma unroll
                for (int cf = 0; cf < 4; ++cf)
                    acc[rf][cf] = __builtin_amdgcn_mfma_f32_16x16x32_f16(af, bf[cf], acc[rf][cf], 0, 0, 0);
            }
        }

        __syncthreads();   // drains next-tile vmcnt + this tile's lgkm; one barrier/iter
        cur ^= 1;
    }
}

// =====================================================================
// K2: Gram  G_b = X_b * X_b^T  (symmetric pairs i<=j, split-K=3)
// 1-D grid 504; b = id&7 so each XCD keeps one batch's panels L2-hot.
// =====================================================================
__global__ __launch_bounds__(256) void k_gram(
    const unsigned short* __restrict__ X, float* __restrict__ Gp)
{
    __shared__ unsigned short lds[4 * 8192];   // 2 bufs x (A,B) x 16KB
    const int id  = blockIdx.x;
    const int b   = id & 7;
    const int r   = id >> 3;          // 0..62
    const int ksl = r / 21;
    int q = r % 21;
    int ti = 0, tj = 0;
    #pragma unroll
    for (int i = 0; i < 6; ++i){ int c = 6 - i; if (q < c){ ti = i; tj = i + q; q = -1; break; } q -= c; }

    static const int kb[4] = {0, 1408, 2752, 4096};

    const unsigned short* XB = X + (long)b * 768 * 4096;

    f32x4 acc[4][4];
    #pragma unroll
    for (int i = 0; i < 4; ++i)
        #pragma unroll
        for (int j = 0; j < 4; ++j) acc[i][j] = (f32x4){0.f, 0.f, 0.f, 0.f};

    kloop(XB, ti * 128, 4096, XB, tj * 128, 4096,
          kb[ksl], kb[ksl + 1], acc, lds, threadIdx.x);

    float* G = Gp + ((long)ksl * 8 + b) * 768 * 768;
    const int lane = threadIdx.x & 63, wave = threadIdx.x >> 6;
    const int wr = (wave >> 1) * 64, wc = (wave & 1) * 64;
    #pragma unroll
    for (int rf = 0; rf < 4; ++rf)
        #pragma unroll
        for (int cf = 0; cf < 4; ++cf){
            int gi = ti * 128 + wr + rf * 16 + 4 * (lane >> 4);
            int gj = tj * 128 + wc + cf * 16 + (lane & 15);
            #pragma unroll
            for (int r2 = 0; r2 < 4; ++r2){
                float v = acc[rf][cf][r2];
                G[(long)(gi + r2) * 768 + gj] = v;
                if (ti != tj) G[(long)gj * 768 + gi + r2] = v;
            }
        }
}

// =====================================================================
// K3: G = sum of 3 split-K partials -> f16
// =====================================================================
__global__ __launch_bounds__(256) void k_sumsplit(
    const float* __restrict__ gp, unsigned short* __restrict__ g16)
{
    const long S = 4718592;  // 8*768*768
    long i = ((long)blockIdx.x * 256 + threadIdx.x) * 4;
    f32x4 a = *(const f32x4*)(gp + i);
    f32x4 b = *(const f32x4*)(gp + S + i);
    f32x4 c = *(const f32x4*)(gp + 2 * S + i);
    unsigned hv[2];
    #pragma unroll
    for (int k2 = 0; k2 < 2; ++k2){
        unsigned short ha = f2h(a[2*k2+0] + b[2*k2+0] + c[2*k2+0]);
        unsigned short hb = f2h(a[2*k2+1] + b[2*k2+1] + c[2*k2+1]);
        hv[k2] = (unsigned)ha | ((unsigned)hb << 16);
    }
    *(u32x2*)(g16 + i) = (u32x2){hv[0], hv[1]};
}

// =====================================================================
// K4: TT_b[eg,c] = sum_c' WvT[eg,c'] * G_b[c,c']
// 1-D grid 288; b = id&7 keeps G_b (1.2 MB) L2-resident per XCD.
// =====================================================================
__global__ __launch_bounds__(256) void k_tt(
    const unsigned short* __restrict__ WT, const unsigned short* __restrict__ G,
    unsigned short* __restrict__ TT)
{
    __shared__ unsigned short lds[4 * 8192];
    const int id = blockIdx.x;
    const int b  = id & 7;
    const int t  = id >> 3;
    const int ti = t % 6, tj = t / 6;

    const unsigned short* A = WT + (long)768 * 768;   // WvT rows
    const unsigned short* B = G + (long)b * 768 * 768;

    f32x4 acc[4][4];
    #pragma unroll
    for (int i = 0; i < 4; ++i)
        #pragma unroll
        for (int j = 0; j < 4; ++j) acc[i][j] = (f32x4){0.f, 0.f, 0.f, 0.f};

    kloop(A, ti * 128, 768, B, tj * 128, 768, 0, 768, acc, lds, threadIdx.x);

    unsigned short* tt = TT + (long)b * 768 * 768;
    const int lane = threadIdx.x & 63, wave = threadIdx.x >> 6;
    const int wr = (wave >> 1) * 64, wc = (wave & 1) * 64;
    #pragma unroll
    for (int rf = 0; rf < 4; ++rf)
        #pragma unroll
        for (int cf = 0; cf < 4; ++cf){
            int gi = ti * 128 + wr + rf * 16 + 4 * (lane >> 4);
            int gj = tj * 128 + wc + cf * 16 + (lane & 15);
            #pragma unroll
            for (int r = 0; r < 4; ++r)
                tt[(long)(gi + r) * 768 + gj] = f2h(acc[rf][cf][r]);
        }
}

// =====================================================================
// K5: ctx_h = scale * WkT_h ·bt· TT_h  + softmax over d -> wT[e][d] f16
// 4 waves per (b,h): waves split K, LDS-reduce, wave 0 does softmax.
// =====================================================================
__global__ __launch_bounds__(256) void k_ctx(
    const unsigned short* __restrict__ WT, const unsigned short* __restrict__ TT,
    unsigned short* __restrict__ wT)
{
    __shared__ float red[3][64][65];
    const int bh = blockIdx.x;
    const int b = bh / 12, h = bh % 12;
    const int lane = threadIdx.x & 63;
    const int wave = threadIdx.x >> 6;

    const unsigned short* A = WT + (long)(h * 64) * 768;
    const unsigned short* B = TT + (long)b * 768 * 768 + (long)(h * 64) * 768;

    f32x4 acc[4][4];
    #pragma unroll
    for (int i = 0; i < 4; ++i)
        #pragma unroll
        for (int j = 0; j < 4; ++j) acc[i][j] = (f32x4){0.f, 0.f, 0.f, 0.f};

    for (int kc = wave * 6; kc < wave * 6 + 6; ++kc){
        const int k0 = kc * 32 + (lane >> 4) * 8;
        f16x8 af[4], bf[4];
        #pragma unroll
        for (int f = 0; f < 4; ++f){
            long ro = (long)(f * 16 + (lane & 15)) * 768 + k0;
            af[f] = *(const f16x8*)(A + ro);
            bf[f] = *(const f16x8*)(B + ro);
        }
        #pragma unroll
        for (int rf = 0; rf < 4; ++rf)
            #pragma unroll
            for (int cf = 0; cf < 4; ++cf)
                acc[rf][cf] = __builtin_amdgcn_mfma_f32_16x16x32_f16(af[rf], bf[cf], acc[rf][cf], 0, 0, 0);
    }

    if (wave > 0){
        #pragma unroll
        for (int rf = 0; rf < 4; ++rf)
            #pragma unroll
            for (int cf = 0; cf < 4; ++cf)
                #pragma unroll
                for (int r = 0; r < 4; ++r)
                    red[wave - 1][lane][(rf * 4 + cf) * 4 + r] = acc[rf][cf][r];
    }
    __syncthreads();
    if (wave != 0) return;

    #pragma unroll
    for (int rf = 0; rf < 4; ++rf)
        #pragma unroll
        for (int cf = 0; cf < 4; ++cf)
            #pragma unroll
            for (int r = 0; r < 4; ++r){
                int idx = (rf * 4 + cf) * 4 + r;
                acc[rf][cf][r] += red[0][lane][idx] + red[1][lane][idx] + red[2][lane][idx];
            }

    // scale + softmax over d (rows); column e lives in lanes {e, e+16, e+32, e+48}
    unsigned short* wout = wT + (long)bh * 4096;
    #pragma unroll
    for (int cf = 0; cf < 4; ++cf){
        float pv[16];
        float m = -3.4e38f;
        #pragma unroll
        for (int rf = 0; rf < 4; ++rf)
            #pragma unroll
            for (int r = 0; r < 4; ++r){
                float s = acc[rf][cf][r] * 0.125f;
                pv[rf * 4 + r] = s;
                m = fmaxf(m, s);
            }
        m = fmaxf(m, __shfl_xor(m, 16));
        m = fmaxf(m, __shfl_xor(m, 32));
        float sum = 0.f;
        #pragma unroll
        for (int k = 0; k < 16; ++k){ pv[k] = __expf(pv[k] - m); sum += pv[k]; }
        sum += __shfl_xor(sum, 16);
        sum += __shfl_xor(sum, 32);
        float inv = 1.f / sum;
        int e = cf * 16 + (lane & 15);
        #pragma unroll
        for (int rf = 0; rf < 4; ++rf)
            #pragma unroll
            for (int r = 0; r < 4; ++r){
                int d = rf * 16 + 4 * (lane >> 4) + r;
                wout[e * 64 + d] = f2h(pv[rf * 4 + r] * inv);
            }
    }
}

// =====================================================================
// K6: apply — o[src][b][n][h*64+e] = sum_d x[b][n][h*64+d] * w[b,h][e][d]
// =====================================================================
__global__ __launch_bounds__(256) void k_apply(
    const float* __restrict__ x1, const float* __restrict__ x2,
    const unsigned short* __restrict__ wT, float* __restrict__ out)
{
    __shared__ float ep[4][64][64];
    const int b = blockIdx.z;
    const int h = blockIdx.y >> 1;
    const int src = blockIdx.y & 1;
    const int lane = threadIdx.x & 63, wave = threadIdx.x >> 6;
    const int n0 = blockIdx.x * 256 + wave * 64;

    const float* x = (src ? x2 : x1) + (long)b * 4096 * 768;
    float* o = out + (long)src * 8 * 4096 * 768 + (long)b * 4096 * 768;

    const unsigned short* W = wT + (long)(b * 12 + h) * 4096;
    f16x8 bw[4][2];
    #pragma unroll
    for (int fe = 0; fe < 4; ++fe)
        #pragma unroll
        for (int ks = 0; ks < 2; ++ks)
            bw[fe][ks] = *(const f16x8*)(W + (fe * 16 + (lane & 15)) * 64 + ks * 32 + (lane >> 4) * 8);

    f32x4 acc[4][4];
    #pragma unroll
    for (int i = 0; i < 4; ++i)
        #pragma unroll
        for (int j = 0; j < 4; ++j) acc[i][j] = (f32x4){0.f, 0.f, 0.f, 0.f};

    #pragma unroll
    for (int rf = 0; rf < 4; ++rf){
        const int row = n0 + rf * 16 + (lane & 15);
        const float* xr = x + (long)row * 768 + h * 64 + (lane >> 4) * 8;
        f32x4 v0 = *(const f32x4*)(xr);
        f32x4 v1 = *(const f32x4*)(xr + 4);
        f32x4 v2 = *(const f32x4*)(xr + 32);
        f32x4 v3 = *(const f32x4*)(xr + 36);
        f16x8 a0, a1;
        #pragma unroll
        for (int t = 0; t < 4; ++t){
            a0[t]     = (_Float16)v0[t];
            a0[t + 4] = (_Float16)v1[t];
            a1[t]     = (_Float16)v2[t];
            a1[t + 4] = (_Float16)v3[t];
        }
        #pragma unroll
        for (int fe = 0; fe < 4; ++fe){
            acc[rf][fe] = __builtin_amdgcn_mfma_f32_16x16x32_f16(a0, bw[fe][0], acc[rf][fe], 0, 0, 0);
            acc[rf][fe] = __builtin_amdgcn_mfma_f32_16x16x32_f16(a1, bw[fe][1], acc[rf][fe], 0, 0, 0);
        }
    }

    // wave-local LDS restage for coalesced float4 stores
    #pragma unroll
    for (int rf = 0; rf < 4; ++rf)
        #pragma unroll
        for (int fe = 0; fe < 4; ++fe)
            #pragma unroll
            for (int r = 0; r < 4; ++r)
                ep[wave][rf * 16 + 4 * (lane >> 4) + r][fe * 16 + (lane & 15)] = acc[rf][fe][r];

    #pragma unroll
    for (int pass = 0; pass < 16; ++pass){
        int rr = pass * 4 + (lane >> 4);
        f32x4 v = *(const f32x4*)&ep[wave][rr][(lane & 15) * 4];
        *(f32x4*)&o[(long)(n0 + rr) * 768 + h * 64 + (lane & 15) * 4] = v;
    }
}

__global__ void k_sentinel(float* o){ o[0] = 1.0e9f; }

// =====================================================================
extern "C" void kernel_launch(void* const* d_in, const int* in_sizes, int n_in,
                              void* d_out, int out_size, void* d_ws, size_t ws_size,
                              hipStream_t stream)
{
    (void)in_sizes; (void)n_in; (void)out_size;
    const float* x1  = (const float*)d_in[0];
    const float* x2  = (const float*)d_in[1];
    const float* seg = (const float*)d_in[2];
    const float* Wkv = (const float*)d_in[3];

    char* Wb = (char*)d_ws;
    unsigned short* X   = (unsigned short*)(Wb);                 // 50,331,648
    unsigned short* WT  = (unsigned short*)(Wb + 50331648);      //  2,359,296
    unsigned short* G   = (unsigned short*)(Wb + 52690944);      //  9,437,184
    unsigned short* TT  = (unsigned short*)(Wb + 62128128);      //  9,437,184
    unsigned short* wT  = (unsigned short*)(Wb + 71565312);      //    786,432
    float*          Gp  = (float*)(Wb + 72351744);               // 56,623,104
    const size_t need = 128974848;

    if (ws_size < need){
        k_sentinel<<<1, 1, 0, stream>>>((float*)d_out);
        return;
    }

    // K1: seg -> X (f16, transposed);  W_kv -> WT (f16, transposed)
    k_transpose_f16<<<dim3(12, 64, 8), 256, 0, stream>>>(
        seg, X, 4096, 768, (long)4096 * 768, (long)768 * 4096);
    k_transpose_f16<<<dim3(24, 12, 1), 256, 0, stream>>>(
        Wkv, WT, 768, 1536, 0, 0);

    // K2: Gram, symmetric pairs, split-K=3, XCD-affine
    k_gram<<<dim3(504), 256, 0, stream>>>(X, Gp);

    // K3: combine split-K partials -> f16
    k_sumsplit<<<dim3(4608), 256, 0, stream>>>(Gp, G);

    // K4: TT = WvT ·bt· G
    k_tt<<<dim3(288), 256, 0, stream>>>(WT, G, TT);

    // K5: ctx + softmax -> wT
    k_ctx<<<dim3(96), 256, 0, stream>>>(WT, TT, wT);

    // K6: apply to both queries
    k_apply<<<dim3(16, 24, 8), 256, 0, stream>>>(x1, x2, wT, (float*)d_out);
}

// Round 5
// 179.127 us; speedup vs baseline: 1.7797x; 1.0776x over previous
//
#include <hip/hip_runtime.h>

#define DI __device__ __forceinline__

typedef float        f32x4 __attribute__((ext_vector_type(4)));
typedef _Float16     f16x8 __attribute__((ext_vector_type(8)));
typedef unsigned int u32x4 __attribute__((ext_vector_type(4)));
typedef unsigned int u32x2 __attribute__((ext_vector_type(2)));

DI unsigned short f2h(float f){
    _Float16 h = (_Float16)f;           // v_cvt_f16_f32, RNE
    return __builtin_bit_cast(unsigned short, h);
}

// ---------- async global->LDS, 16B per lane ----------
DI void gl_lds16(const void* g, void* l){
    __builtin_amdgcn_global_load_lds(
        (const __attribute__((address_space(1))) unsigned int*)g,
        (__attribute__((address_space(3))) unsigned int*)l, 16, 0, 0);
}

// =====================================================================
// K1: tiled transpose + f16 convert.  in[b][r][c] f32 -> o16[b][c][r] f16
// =====================================================================
__global__ __launch_bounds__(256) void k_transpose_f16(
    const float* __restrict__ in, unsigned short* __restrict__ o16,
    int rows, int cols, long ibs, long obs)
{
    __shared__ float t[64][65];
    const int b  = blockIdx.z;
    const int r0 = blockIdx.y * 64, c0 = blockIdx.x * 64;
    const int tid = threadIdx.x;
    const float* ib = in + (long)b * ibs;

    #pragma unroll
    for (int i = 0; i < 4; ++i){
        int r  = (tid >> 4) + i * 16;
        int cq = (tid & 15) * 4;
        f32x4 v = *(const f32x4*)&ib[(long)(r0 + r) * cols + c0 + cq];
        t[r][cq+0] = v[0]; t[r][cq+1] = v[1]; t[r][cq+2] = v[2]; t[r][cq+3] = v[3];
    }
    __syncthreads();

    const int c  = tid >> 2;
    const int ms = (tid & 3) * 16;
    unsigned hv[8];
    #pragma unroll
    for (int k2 = 0; k2 < 8; ++k2){
        unsigned short ha = f2h(t[ms + 2*k2 + 0][c]);
        unsigned short hb = f2h(t[ms + 2*k2 + 1][c]);
        hv[k2] = (unsigned)ha | ((unsigned)hb << 16);
    }
    long o = (long)b * obs + (long)(c0 + c) * rows + r0 + ms;
    u32x4 H0 = {hv[0],hv[1],hv[2],hv[3]}, H1 = {hv[4],hv[5],hv[6],hv[7]};
    *(u32x4*)&o16[o]     = H0;
    *(u32x4*)&o16[o + 8] = H1;
}

// =====================================================================
// shared bt-GEMM machinery: C[i,j] += sum_k A[i,k]*B[j,k]
// LDS tiles 128x64 f16, double-buffered. gload_lds writes LINEAR dest;
// XOR swizzle (colb ^= (row&7)<<4) applied to GLOBAL source (involution);
// frag_ld reads swizzled (rule 21 / m173).
// =====================================================================
DI void stage_lds(const unsigned short* __restrict__ src, long stride,
                  int row0, int k0, unsigned short* tile, int tid)
{
    #pragma unroll
    for (int it = 0; it < 4; ++it){
        int D    = (it * 256 + tid) * 16;                 // dest byte (linear)
        int row  = D >> 7;
        int colb = (D & 127) ^ ((row & 7) << 4);          // inverse-swizzled source col
        const char* g = (const char*)(src + (long)(row0 + row) * stride + k0) + colb;
        gl_lds16(g, (char*)tile + D);
    }
}

DI f16x8 frag_ld(const unsigned short* tile, int row, int kc16)
{
    int logical = (row << 7) + (kc16 << 4);
    int phys    = logical ^ ((row & 7) << 4);
    return *(const f16x8*)((const char*)tile + phys);
}

// reg-staged B = sum of 3 f16 split-K partials (T14 split: load early, write late)
DI void ldB3(const unsigned short* __restrict__ g0, long S16, long stride,
             int row0, int k0, int tid, f16x8 r0[4], f16x8 r1[4], f16x8 r2[4])
{
    #pragma unroll
    for (int it = 0; it < 4; ++it){
        int D    = (it * 256 + tid) * 16;
        int row  = D >> 7;
        int colb = D & 127;
        long off = (long)(row0 + row) * stride + k0 + (colb >> 1);
        r0[it] = *(const f16x8*)(g0 + off);
        r1[it] = *(const f16x8*)(g0 + S16 + off);
        r2[it] = *(const f16x8*)(g0 + 2 * S16 + off);
    }
}
DI void wrB3(unsigned short* tile, int tid, f16x8 r0[4], f16x8 r1[4], f16x8 r2[4])
{
    #pragma unroll
    for (int it = 0; it < 4; ++it){
        int D    = (it * 256 + tid) * 16;
        int row  = D >> 7;
        int colb = D & 127;
        f16x8 s;
        #pragma unroll
        for (int t = 0; t < 8; ++t)
            s[t] = (_Float16)((float)r0[it][t] + (float)r1[it][t] + (float)r2[it][t]);
        int phys = (D & ~127) | (colb ^ ((row & 7) << 4));   // swizzled dest (pairs with frag_ld)
        *(f16x8*)((char*)tile + phys) = s;
    }
}

DI void mfma_tile(const unsigned short* TA, const unsigned short* TB,
                  int wr, int wc, int lane, f32x4 acc[4][4])
{
    #pragma unroll
    for (int ks = 0; ks < 2; ++ks){
        const int kc = ks * 4 + (lane >> 4);
        f16x8 bf[4];
        #pragma unroll
        for (int cf = 0; cf < 4; ++cf)
            bf[cf] = frag_ld(TB, wc + cf * 16 + (lane & 15), kc);
        #pragma unroll
        for (int rf = 0; rf < 4; ++rf){
            f16x8 af = frag_ld(TA, wr + rf * 16 + (lane & 15), kc);
            #pragma unroll
            for (int cf = 0; cf < 4; ++cf)
                acc[rf][cf] = __builtin_amdgcn_mfma_f32_16x16x32_f16(af, bf[cf], acc[rf][cf], 0, 0, 0);
        }
    }
}

DI void kloop(const unsigned short* a, int rowA0, long sA,
              const unsigned short* b, int rowB0, long sB,
              int kbeg, int kend, f32x4 acc[4][4], unsigned short* lds, int tid)
{
    const int lane = tid & 63;
    const int wave = tid >> 6;
    const int wr = (wave >> 1) * 64, wc = (wave & 1) * 64;

    stage_lds(a, sA, rowA0, kbeg, lds,        tid);
    stage_lds(b, sB, rowB0, kbeg, lds + 8192, tid);
    __syncthreads();

    int cur = 0;
    for (int k0 = kbeg; k0 < kend; k0 += 64){
        const unsigned short* TA = lds + cur * 16384;
        const int kn = k0 + 64;
        if (kn < kend){
            unsigned short* NA = lds + (cur ^ 1) * 16384;
            stage_lds(a, sA, rowA0, kn, NA,        tid);
            stage_lds(b, sB, rowB0, kn, NA + 8192, tid);
        }
        mfma_tile(TA, TA + 8192, wr, wc, lane, acc);
        __syncthreads();   // drains next-tile vmcnt + this tile's lgkm
        cur ^= 1;
    }
}

// =====================================================================
// K2: Gram  G_b = X_b * X_b^T  (symmetric pairs i<=j, split-K=3)
// 1-D grid 504; b = id&7 so each XCD keeps one batch's panels L2-hot.
// Writes f16 partials Gp16[ksl][b][768][768].
// =====================================================================
__global__ __launch_bounds__(256) void k_gram(
    const unsigned short* __restrict__ X, unsigned short* __restrict__ Gp16)
{
    __shared__ unsigned short lds[4 * 8192];   // 2 bufs x (A,B) x 16KB
    const int id  = blockIdx.x;
    const int b   = id & 7;
    const int r   = id >> 3;          // 0..62
    const int ksl = r / 21;
    int q = r % 21;
    int ti = 0, tj = 0;
    #pragma unroll
    for (int i = 0; i < 6; ++i){ int c = 6 - i; if (q < c){ ti = i; tj = i + q; q = -1; break; } q -= c; }

    static const int kb[4] = {0, 1408, 2752, 4096};

    const unsigned short* XB = X + (long)b * 768 * 4096;

    f32x4 acc[4][4];
    #pragma unroll
    for (int i = 0; i < 4; ++i)
        #pragma unroll
        for (int j = 0; j < 4; ++j) acc[i][j] = (f32x4){0.f, 0.f, 0.f, 0.f};

    kloop(XB, ti * 128, 4096, XB, tj * 128, 4096,
          kb[ksl], kb[ksl + 1], acc, lds, threadIdx.x);

    unsigned short* G = Gp16 + ((long)ksl * 8 + b) * 768 * 768;
    const int lane = threadIdx.x & 63, wave = threadIdx.x >> 6;
    const int wr = (wave >> 1) * 64, wc = (wave & 1) * 64;
    #pragma unroll
    for (int rf = 0; rf < 4; ++rf)
        #pragma unroll
        for (int cf = 0; cf < 4; ++cf){
            int gi = ti * 128 + wr + rf * 16 + 4 * (lane >> 4);
            int gj = tj * 128 + wc + cf * 16 + (lane & 15);
            unsigned short h4[4];
            #pragma unroll
            for (int r2 = 0; r2 < 4; ++r2){
                h4[r2] = f2h(acc[rf][cf][r2]);
                G[(long)(gi + r2) * 768 + gj] = h4[r2];
            }
            if (ti != tj){
                // transposed dual-write: gi multiple of 4 -> aligned 8B store
                u32x2 p = { (unsigned)h4[0] | ((unsigned)h4[1] << 16),
                            (unsigned)h4[2] | ((unsigned)h4[3] << 16) };
                *(u32x2*)(G + (long)gj * 768 + gi) = p;
            }
        }
}

// =====================================================================
// K4: TT_b[eg,c] = sum_c' WvT[eg,c'] * (Gp0+Gp1+Gp2)_b[c,c']
// B staged from 3 f16 partials: loads issued BEFORE MFMA, summed+written after.
// 1-D grid 288; b = id&7 keeps Gp16_b (3.5 MB) L2-resident per XCD.
// =====================================================================
__global__ __launch_bounds__(256) void k_tt(
    const unsigned short* __restrict__ WT, const unsigned short* __restrict__ Gp16,
    unsigned short* __restrict__ TT)
{
    __shared__ unsigned short lds[4 * 8192];
    const long S16 = 4718592;   // 8*768*768
    const int id = blockIdx.x;
    const int b  = id & 7;
    const int t  = id >> 3;
    const int ti = t % 6, tj = t / 6;
    const int tid = threadIdx.x;

    const unsigned short* A  = WT + (long)768 * 768;     // WvT rows
    const unsigned short* G0 = Gp16 + (long)b * 768 * 768;

    f32x4 acc[4][4];
    #pragma unroll
    for (int i = 0; i < 4; ++i)
        #pragma unroll
        for (int j = 0; j < 4; ++j) acc[i][j] = (f32x4){0.f, 0.f, 0.f, 0.f};

    const int lane = tid & 63;
    const int wave = tid >> 6;
    const int wr = (wave >> 1) * 64, wc = (wave & 1) * 64;

    // prologue: first K-tile
    {
        f16x8 r0[4], r1[4], r2[4];
        ldB3(G0, S16, 768, tj * 128, 0, tid, r0, r1, r2);
        stage_lds(A, 768, ti * 128, 0, lds, tid);
        wrB3(lds + 8192, tid, r0, r1, r2);
        __syncthreads();
    }

    int cur = 0;
    for (int k0 = 0; k0 < 768; k0 += 64){
        const unsigned short* TA = lds + cur * 16384;
        const int kn = k0 + 64;
        f16x8 r0[4], r1[4], r2[4];
        if (kn < 768){
            ldB3(G0, S16, 768, tj * 128, kn, tid, r0, r1, r2);   // loads fly under MFMA
            stage_lds(A, 768, ti * 128, kn, lds + (cur ^ 1) * 16384, tid);
        }
        mfma_tile(TA, TA + 8192, wr, wc, lane, acc);
        if (kn < 768)
            wrB3(lds + (cur ^ 1) * 16384 + 8192, tid, r0, r1, r2);  // vmcnt-wait lands here
        __syncthreads();
        cur ^= 1;
    }

    unsigned short* tt = TT + (long)b * 768 * 768;
    #pragma unroll
    for (int rf = 0; rf < 4; ++rf)
        #pragma unroll
        for (int cf = 0; cf < 4; ++cf){
            int gi = ti * 128 + wr + rf * 16 + 4 * (lane >> 4);
            int gj = tj * 128 + wc + cf * 16 + (lane & 15);
            #pragma unroll
            for (int r = 0; r < 4; ++r)
                tt[(long)(gi + r) * 768 + gj] = f2h(acc[rf][cf][r]);
        }
}

// =====================================================================
// K5: ctx_h = scale * WkT_h ·bt· TT_h  + softmax over d -> wT[e][d] f16
// 4 waves per (b,h): waves split K, LDS-reduce, wave 0 does softmax.
// =====================================================================
__global__ __launch_bounds__(256) void k_ctx(
    const unsigned short* __restrict__ WT, const unsigned short* __restrict__ TT,
    unsigned short* __restrict__ wT)
{
    __shared__ float red[3][64][65];
    const int bh = blockIdx.x;
    const int b = bh / 12, h = bh % 12;
    const int lane = threadIdx.x & 63;
    const int wave = threadIdx.x >> 6;

    const unsigned short* A = WT + (long)(h * 64) * 768;
    const unsigned short* B = TT + (long)b * 768 * 768 + (long)(h * 64) * 768;

    f32x4 acc[4][4];
    #pragma unroll
    for (int i = 0; i < 4; ++i)
        #pragma unroll
        for (int j = 0; j < 4; ++j) acc[i][j] = (f32x4){0.f, 0.f, 0.f, 0.f};

    for (int kc = wave * 6; kc < wave * 6 + 6; ++kc){
        const int k0 = kc * 32 + (lane >> 4) * 8;
        f16x8 af[4], bf[4];
        #pragma unroll
        for (int f = 0; f < 4; ++f){
            long ro = (long)(f * 16 + (lane & 15)) * 768 + k0;
            af[f] = *(const f16x8*)(A + ro);
            bf[f] = *(const f16x8*)(B + ro);
        }
        #pragma unroll
        for (int rf = 0; rf < 4; ++rf)
            #pragma unroll
            for (int cf = 0; cf < 4; ++cf)
                acc[rf][cf] = __builtin_amdgcn_mfma_f32_16x16x32_f16(af[rf], bf[cf], acc[rf][cf], 0, 0, 0);
    }

    if (wave > 0){
        #pragma unroll
        for (int rf = 0; rf < 4; ++rf)
            #pragma unroll
            for (int cf = 0; cf < 4; ++cf)
                #pragma unroll
                for (int r = 0; r < 4; ++r)
                    red[wave - 1][lane][(rf * 4 + cf) * 4 + r] = acc[rf][cf][r];
    }
    __syncthreads();
    if (wave != 0) return;

    #pragma unroll
    for (int rf = 0; rf < 4; ++rf)
        #pragma unroll
        for (int cf = 0; cf < 4; ++cf)
            #pragma unroll
            for (int r = 0; r < 4; ++r){
                int idx = (rf * 4 + cf) * 4 + r;
                acc[rf][cf][r] += red[0][lane][idx] + red[1][lane][idx] + red[2][lane][idx];
            }

    // scale + softmax over d (rows); column e lives in lanes {e, e+16, e+32, e+48}
    unsigned short* wout = wT + (long)bh * 4096;
    #pragma unroll
    for (int cf = 0; cf < 4; ++cf){
        float pv[16];
        float m = -3.4e38f;
        #pragma unroll
        for (int rf = 0; rf < 4; ++rf)
            #pragma unroll
            for (int r = 0; r < 4; ++r){
                float s = acc[rf][cf][r] * 0.125f;
                pv[rf * 4 + r] = s;
                m = fmaxf(m, s);
            }
        m = fmaxf(m, __shfl_xor(m, 16));
        m = fmaxf(m, __shfl_xor(m, 32));
        float sum = 0.f;
        #pragma unroll
        for (int k = 0; k < 16; ++k){ pv[k] = __expf(pv[k] - m); sum += pv[k]; }
        sum += __shfl_xor(sum, 16);
        sum += __shfl_xor(sum, 32);
        float inv = 1.f / sum;
        int e = cf * 16 + (lane & 15);
        #pragma unroll
        for (int rf = 0; rf < 4; ++rf)
            #pragma unroll
            for (int r = 0; r < 4; ++r){
                int d = rf * 16 + 4 * (lane >> 4) + r;
                wout[e * 64 + d] = f2h(pv[rf * 4 + r] * inv);
            }
    }
}

// =====================================================================
// K6: apply — o[src][b][n][h*64+e] = sum_d x[b][n][h*64+d] * w[b,h][e][d]
// =====================================================================
__global__ __launch_bounds__(256) void k_apply(
    const float* __restrict__ x1, const float* __restrict__ x2,
    const unsigned short* __restrict__ wT, float* __restrict__ out)
{
    __shared__ float ep[4][64][64];
    const int b = blockIdx.z;
    const int h = blockIdx.y >> 1;
    const int src = blockIdx.y & 1;
    const int lane = threadIdx.x & 63, wave = threadIdx.x >> 6;
    const int n0 = blockIdx.x * 256 + wave * 64;

    const float* x = (src ? x2 : x1) + (long)b * 4096 * 768;
    float* o = out + (long)src * 8 * 4096 * 768 + (long)b * 4096 * 768;

    const unsigned short* W = wT + (long)(b * 12 + h) * 4096;
    f16x8 bw[4][2];
    #pragma unroll
    for (int fe = 0; fe < 4; ++fe)
        #pragma unroll
        for (int ks = 0; ks < 2; ++ks)
            bw[fe][ks] = *(const f16x8*)(W + (fe * 16 + (lane & 15)) * 64 + ks * 32 + (lane >> 4) * 8);

    f32x4 acc[4][4];
    #pragma unroll
    for (int i = 0; i < 4; ++i)
        #pragma unroll
        for (int j = 0; j < 4; ++j) acc[i][j] = (f32x4){0.f, 0.f, 0.f, 0.f};

    #pragma unroll
    for (int rf = 0; rf < 4; ++rf){
        const int row = n0 + rf * 16 + (lane & 15);
        const float* xr = x + (long)row * 768 + h * 64 + (lane >> 4) * 8;
        f32x4 v0 = *(const f32x4*)(xr);
        f32x4 v1 = *(const f32x4*)(xr + 4);
        f32x4 v2 = *(const f32x4*)(xr + 32);
        f32x4 v3 = *(const f32x4*)(xr + 36);
        f16x8 a0, a1;
        #pragma unroll
        for (int t = 0; t < 4; ++t){
            a0[t]     = (_Float16)v0[t];
            a0[t + 4] = (_Float16)v1[t];
            a1[t]     = (_Float16)v2[t];
            a1[t + 4] = (_Float16)v3[t];
        }
        #pragma unroll
        for (int fe = 0; fe < 4; ++fe){
            acc[rf][fe] = __builtin_amdgcn_mfma_f32_16x16x32_f16(a0, bw[fe][0], acc[rf][fe], 0, 0, 0);
            acc[rf][fe] = __builtin_amdgcn_mfma_f32_16x16x32_f16(a1, bw[fe][1], acc[rf][fe], 0, 0, 0);
        }
    }

    // wave-local LDS restage for coalesced float4 stores
    #pragma unroll
    for (int rf = 0; rf < 4; ++rf)
        #pragma unroll
        for (int fe = 0; fe < 4; ++fe)
            #pragma unroll
            for (int r = 0; r < 4; ++r)
                ep[wave][rf * 16 + 4 * (lane >> 4) + r][fe * 16 + (lane & 15)] = acc[rf][fe][r];

    #pragma unroll
    for (int pass = 0; pass < 16; ++pass){
        int rr = pass * 4 + (lane >> 4);
        f32x4 v = *(const f32x4*)&ep[wave][rr][(lane & 15) * 4];
        *(f32x4*)&o[(long)(n0 + rr) * 768 + h * 64 + (lane & 15) * 4] = v;
    }
}

__global__ void k_sentinel(float* o){ o[0] = 1.0e9f; }

// =====================================================================
extern "C" void kernel_launch(void* const* d_in, const int* in_sizes, int n_in,
                              void* d_out, int out_size, void* d_ws, size_t ws_size,
                              hipStream_t stream)
{
    (void)in_sizes; (void)n_in; (void)out_size;
    const float* x1  = (const float*)d_in[0];
    const float* x2  = (const float*)d_in[1];
    const float* seg = (const float*)d_in[2];
    const float* Wkv = (const float*)d_in[3];

    char* Wb = (char*)d_ws;
    unsigned short* X    = (unsigned short*)(Wb);                 // 50,331,648
    unsigned short* WT   = (unsigned short*)(Wb + 50331648);      //  2,359,296
    unsigned short* TT   = (unsigned short*)(Wb + 52690944);      //  9,437,184
    unsigned short* wT   = (unsigned short*)(Wb + 62128128);      //    786,432
    unsigned short* Gp16 = (unsigned short*)(Wb + 62914560);      // 28,311,552
    const size_t need = 91226112;

    if (ws_size < need){
        k_sentinel<<<1, 1, 0, stream>>>((float*)d_out);
        return;
    }

    // K1: seg -> X (f16, transposed);  W_kv -> WT (f16, transposed)
    k_transpose_f16<<<dim3(12, 64, 8), 256, 0, stream>>>(
        seg, X, 4096, 768, (long)4096 * 768, (long)768 * 4096);
    k_transpose_f16<<<dim3(24, 12, 1), 256, 0, stream>>>(
        Wkv, WT, 768, 1536, 0, 0);

    // K2: Gram, symmetric pairs, split-K=3, XCD-affine, f16 partials
    k_gram<<<dim3(504), 256, 0, stream>>>(X, Gp16);

    // K4: TT = WvT ·bt· (sum of partials)
    k_tt<<<dim3(288), 256, 0, stream>>>(WT, Gp16, TT);

    // K5: ctx + softmax -> wT
    k_ctx<<<dim3(96), 256, 0, stream>>>(WT, TT, wT);

    // K6: apply to both queries
    k_apply<<<dim3(16, 24, 8), 256, 0, stream>>>(x1, x2, wT, (float*)d_out);
}

// Round 6
// 178.099 us; speedup vs baseline: 1.7900x; 1.0058x over previous
//
#include <hip/hip_runtime.h>

#define DI __device__ __forceinline__

typedef float        f32x4 __attribute__((ext_vector_type(4)));
typedef _Float16     f16x8 __attribute__((ext_vector_type(8)));
typedef unsigned int u32x4 __attribute__((ext_vector_type(4)));
typedef unsigned int u32x2 __attribute__((ext_vector_type(2)));

DI unsigned short f2h(float f){
    _Float16 h = (_Float16)f;           // v_cvt_f16_f32, RNE
    return __builtin_bit_cast(unsigned short, h);
}

// ---------- async global->LDS, 16B per lane ----------
DI void gl_lds16(const void* g, void* l){
    __builtin_amdgcn_global_load_lds(
        (const __attribute__((address_space(1))) unsigned int*)g,
        (__attribute__((address_space(3))) unsigned int*)l, 16, 0, 0);
}

// =====================================================================
// K1: tiled transpose + f16 convert.  in[b][r][c] f32 -> o16[b][c][r] f16
// =====================================================================
__global__ __launch_bounds__(256) void k_transpose_f16(
    const float* __restrict__ in, unsigned short* __restrict__ o16,
    int rows, int cols, long ibs, long obs)
{
    __shared__ float t[64][65];
    const int b  = blockIdx.z;
    const int r0 = blockIdx.y * 64, c0 = blockIdx.x * 64;
    const int tid = threadIdx.x;
    const float* ib = in + (long)b * ibs;

    #pragma unroll
    for (int i = 0; i < 4; ++i){
        int r  = (tid >> 4) + i * 16;
        int cq = (tid & 15) * 4;
        f32x4 v = *(const f32x4*)&ib[(long)(r0 + r) * cols + c0 + cq];
        t[r][cq+0] = v[0]; t[r][cq+1] = v[1]; t[r][cq+2] = v[2]; t[r][cq+3] = v[3];
    }
    __syncthreads();

    const int c  = tid >> 2;
    const int ms = (tid & 3) * 16;
    unsigned hv[8];
    #pragma unroll
    for (int k2 = 0; k2 < 8; ++k2){
        unsigned short ha = f2h(t[ms + 2*k2 + 0][c]);
        unsigned short hb = f2h(t[ms + 2*k2 + 1][c]);
        hv[k2] = (unsigned)ha | ((unsigned)hb << 16);
    }
    long o = (long)b * obs + (long)(c0 + c) * rows + r0 + ms;
    u32x4 H0 = {hv[0],hv[1],hv[2],hv[3]}, H1 = {hv[4],hv[5],hv[6],hv[7]};
    *(u32x4*)&o16[o]     = H0;
    *(u32x4*)&o16[o + 8] = H1;
}

// =====================================================================
// shared bt-GEMM machinery: C[i,j] += sum_k A[i,k]*B[j,k]
// LDS tiles 128x64 f16, double-buffered. gload_lds writes LINEAR dest;
// XOR swizzle (colb ^= (row&7)<<4) applied to GLOBAL source (involution);
// frag_ld reads swizzled (rule 21 / m173).
// TPB=512: 8 waves, per-wave output 64x32 (RF=4, CF=2) -> 4 waves/SIMD TLP.
// =====================================================================
template<int TPB>
DI void stage_lds(const unsigned short* __restrict__ src, long stride,
                  int row0, int k0, unsigned short* tile, int tid)
{
    #pragma unroll
    for (int it = 0; it < 1024 / TPB; ++it){
        int D    = (it * TPB + tid) * 16;                 // dest byte (linear)
        int row  = D >> 7;
        int colb = (D & 127) ^ ((row & 7) << 4);          // inverse-swizzled source col
        const char* g = (const char*)(src + (long)(row0 + row) * stride + k0) + colb;
        gl_lds16(g, (char*)tile + D);
    }
}

DI f16x8 frag_ld(const unsigned short* tile, int row, int kc16)
{
    int logical = (row << 7) + (kc16 << 4);
    int phys    = logical ^ ((row & 7) << 4);
    return *(const f16x8*)((const char*)tile + phys);
}

template<int RF, int CF>
DI void mfma_tile(const unsigned short* TA, const unsigned short* TB,
                  int wr, int wc, int lane, f32x4 acc[RF][CF])
{
    #pragma unroll
    for (int ks = 0; ks < 2; ++ks){
        const int kc = ks * 4 + (lane >> 4);
        f16x8 bf[CF];
        #pragma unroll
        for (int cf = 0; cf < CF; ++cf)
            bf[cf] = frag_ld(TB, wc + cf * 16 + (lane & 15), kc);
        #pragma unroll
        for (int rf = 0; rf < RF; ++rf){
            f16x8 af = frag_ld(TA, wr + rf * 16 + (lane & 15), kc);
            #pragma unroll
            for (int cf = 0; cf < CF; ++cf)
                acc[rf][cf] = __builtin_amdgcn_mfma_f32_16x16x32_f16(af, bf[cf], acc[rf][cf], 0, 0, 0);
        }
    }
}

template<int TPB, int RF, int CF>
DI void kloop(const unsigned short* a, int rowA0, long sA,
              const unsigned short* b, int rowB0, long sB,
              int kbeg, int kend, f32x4 acc[RF][CF], unsigned short* lds, int tid)
{
    const int lane = tid & 63;
    const int wave = tid >> 6;
    const int WCN  = 128 / (CF * 16);                 // col-waves
    const int wr = (wave / WCN) * (RF * 16);
    const int wc = (wave % WCN) * (CF * 16);

    stage_lds<TPB>(a, sA, rowA0, kbeg, lds,        tid);
    stage_lds<TPB>(b, sB, rowB0, kbeg, lds + 8192, tid);
    __syncthreads();

    int cur = 0;
    for (int k0 = kbeg; k0 < kend; k0 += 64){
        const unsigned short* TA = lds + cur * 16384;
        const int kn = k0 + 64;
        if (kn < kend){
            unsigned short* NA = lds + (cur ^ 1) * 16384;
            stage_lds<TPB>(a, sA, rowA0, kn, NA,        tid);
            stage_lds<TPB>(b, sB, rowB0, kn, NA + 8192, tid);
        }
        mfma_tile<RF, CF>(TA, TA + 8192, wr, wc, lane, acc);
        __syncthreads();   // drains next-tile vmcnt + this tile's lgkm
        cur ^= 1;
    }
}

// =====================================================================
// K2: Gram  G_b = X_b * X_b^T  (symmetric pairs i<=j, split-K=3)
// 1-D grid 504 x 512 thr; b = id&7 keeps each batch's panels on one XCD.
// Writes f16 partials Gp16[ksl][b][768][768].
// =====================================================================
__global__ __launch_bounds__(512) void k_gram(
    const unsigned short* __restrict__ X, unsigned short* __restrict__ Gp16)
{
    __shared__ unsigned short lds[4 * 8192];   // 2 bufs x (A,B) x 16KB
    const int id  = blockIdx.x;
    const int b   = id & 7;
    const int r   = id >> 3;          // 0..62
    const int ksl = r / 21;
    int q = r % 21;
    int ti = 0, tj = 0;
    #pragma unroll
    for (int i = 0; i < 6; ++i){ int c = 6 - i; if (q < c){ ti = i; tj = i + q; q = -1; break; } q -= c; }

    static const int kb[4] = {0, 1408, 2752, 4096};

    const unsigned short* XB = X + (long)b * 768 * 4096;

    f32x4 acc[4][2];
    #pragma unroll
    for (int i = 0; i < 4; ++i)
        #pragma unroll
        for (int j = 0; j < 2; ++j) acc[i][j] = (f32x4){0.f, 0.f, 0.f, 0.f};

    kloop<512, 4, 2>(XB, ti * 128, 4096, XB, tj * 128, 4096,
                     kb[ksl], kb[ksl + 1], acc, lds, threadIdx.x);

    unsigned short* G = Gp16 + ((long)ksl * 8 + b) * 768 * 768;
    const int lane = threadIdx.x & 63, wave = threadIdx.x >> 6;
    const int wr = (wave >> 2) * 64, wc = (wave & 3) * 32;
    #pragma unroll
    for (int rf = 0; rf < 4; ++rf)
        #pragma unroll
        for (int cf = 0; cf < 2; ++cf){
            int gi = ti * 128 + wr + rf * 16 + 4 * (lane >> 4);
            int gj = tj * 128 + wc + cf * 16 + (lane & 15);
            unsigned short h4[4];
            #pragma unroll
            for (int r2 = 0; r2 < 4; ++r2){
                h4[r2] = f2h(acc[rf][cf][r2]);
                G[(long)(gi + r2) * 768 + gj] = h4[r2];
            }
            if (ti != tj){
                // transposed dual-write: gi multiple of 4 -> aligned 8B store
                u32x2 p = { (unsigned)h4[0] | ((unsigned)h4[1] << 16),
                            (unsigned)h4[2] | ((unsigned)h4[3] << 16) };
                *(u32x2*)(G + (long)gj * 768 + gi) = p;
            }
        }
}

// =====================================================================
// K4: TT_b[eg,c] = sum_c' WvT[eg,c'] * (Gp0+Gp1+Gp2)_b[c,c']
// B staged from 3 f16 partials: loads issued BEFORE MFMA, summed+written after
// (T14 split). 1-D grid 288 x 512 thr; b = id&7 keeps Gp16_b L2-resident.
// =====================================================================
DI void ldB3(const unsigned short* __restrict__ g0, long S16, long stride,
             int row0, int k0, int tid, f16x8 r0[2], f16x8 r1[2], f16x8 r2[2])
{
    #pragma unroll
    for (int it = 0; it < 2; ++it){
        int D    = (it * 512 + tid) * 16;
        int row  = D >> 7;
        int colb = D & 127;
        long off = (long)(row0 + row) * stride + k0 + (colb >> 1);
        r0[it] = *(const f16x8*)(g0 + off);
        r1[it] = *(const f16x8*)(g0 + S16 + off);
        r2[it] = *(const f16x8*)(g0 + 2 * S16 + off);
    }
}
DI void wrB3(unsigned short* tile, int tid, f16x8 r0[2], f16x8 r1[2], f16x8 r2[2])
{
    #pragma unroll
    for (int it = 0; it < 2; ++it){
        int D    = (it * 512 + tid) * 16;
        int row  = D >> 7;
        int colb = D & 127;
        f16x8 s;
        #pragma unroll
        for (int t = 0; t < 8; ++t)
            s[t] = (_Float16)((float)r0[it][t] + (float)r1[it][t] + (float)r2[it][t]);
        int phys = (D & ~127) | (colb ^ ((row & 7) << 4));   // swizzled dest (pairs with frag_ld)
        *(f16x8*)((char*)tile + phys) = s;
    }
}

__global__ __launch_bounds__(512) void k_tt(
    const unsigned short* __restrict__ WT, const unsigned short* __restrict__ Gp16,
    unsigned short* __restrict__ TT)
{
    __shared__ unsigned short lds[4 * 8192];
    const long S16 = 4718592;   // 8*768*768
    const int id = blockIdx.x;
    const int b  = id & 7;
    const int t  = id >> 3;
    const int ti = t % 6, tj = t / 6;
    const int tid = threadIdx.x;

    const unsigned short* A  = WT + (long)768 * 768;     // WvT rows
    const unsigned short* G0 = Gp16 + (long)b * 768 * 768;

    f32x4 acc[4][2];
    #pragma unroll
    for (int i = 0; i < 4; ++i)
        #pragma unroll
        for (int j = 0; j < 2; ++j) acc[i][j] = (f32x4){0.f, 0.f, 0.f, 0.f};

    const int lane = tid & 63;
    const int wave = tid >> 6;
    const int wr = (wave >> 2) * 64, wc = (wave & 3) * 32;

    // prologue: first K-tile
    {
        f16x8 r0[2], r1[2], r2[2];
        ldB3(G0, S16, 768, tj * 128, 0, tid, r0, r1, r2);
        stage_lds<512>(A, 768, ti * 128, 0, lds, tid);
        wrB3(lds + 8192, tid, r0, r1, r2);
        __syncthreads();
    }

    int cur = 0;
    for (int k0 = 0; k0 < 768; k0 += 64){
        const unsigned short* TA = lds + cur * 16384;
        const int kn = k0 + 64;
        f16x8 r0[2], r1[2], r2[2];
        if (kn < 768){
            ldB3(G0, S16, 768, tj * 128, kn, tid, r0, r1, r2);   // loads fly under MFMA
            stage_lds<512>(A, 768, ti * 128, kn, lds + (cur ^ 1) * 16384, tid);
        }
        mfma_tile<4, 2>(TA, TA + 8192, wr, wc, lane, acc);
        if (kn < 768)
            wrB3(lds + (cur ^ 1) * 16384 + 8192, tid, r0, r1, r2);  // vmcnt-wait lands here
        __syncthreads();
        cur ^= 1;
    }

    unsigned short* tt = TT + (long)b * 768 * 768;
    #pragma unroll
    for (int rf = 0; rf < 4; ++rf)
        #pragma unroll
        for (int cf = 0; cf < 2; ++cf){
            int gi = ti * 128 + wr + rf * 16 + 4 * (lane >> 4);
            int gj = tj * 128 + wc + cf * 16 + (lane & 15);
            #pragma unroll
            for (int r = 0; r < 4; ++r)
                tt[(long)(gi + r) * 768 + gj] = f2h(acc[rf][cf][r]);
        }
}

// =====================================================================
// K5: ctx_h = scale * WkT_h ·bt· TT_h  + softmax over d -> wT[e][d] f16
// 4 waves per (b,h): waves split K, LDS-reduce, wave 0 does softmax.
// =====================================================================
__global__ __launch_bounds__(256) void k_ctx(
    const unsigned short* __restrict__ WT, const unsigned short* __restrict__ TT,
    unsigned short* __restrict__ wT)
{
    __shared__ float red[3][64][65];
    const int bh = blockIdx.x;
    const int b = bh / 12, h = bh % 12;
    const int lane = threadIdx.x & 63;
    const int wave = threadIdx.x >> 6;

    const unsigned short* A = WT + (long)(h * 64) * 768;
    const unsigned short* B = TT + (long)b * 768 * 768 + (long)(h * 64) * 768;

    f32x4 acc[4][4];
    #pragma unroll
    for (int i = 0; i < 4; ++i)
        #pragma unroll
        for (int j = 0; j < 4; ++j) acc[i][j] = (f32x4){0.f, 0.f, 0.f, 0.f};

    for (int kc = wave * 6; kc < wave * 6 + 6; ++kc){
        const int k0 = kc * 32 + (lane >> 4) * 8;
        f16x8 af[4], bf[4];
        #pragma unroll
        for (int f = 0; f < 4; ++f){
            long ro = (long)(f * 16 + (lane & 15)) * 768 + k0;
            af[f] = *(const f16x8*)(A + ro);
            bf[f] = *(const f16x8*)(B + ro);
        }
        #pragma unroll
        for (int rf = 0; rf < 4; ++rf)
            #pragma unroll
            for (int cf = 0; cf < 4; ++cf)
                acc[rf][cf] = __builtin_amdgcn_mfma_f32_16x16x32_f16(af[rf], bf[cf], acc[rf][cf], 0, 0, 0);
    }

    if (wave > 0){
        #pragma unroll
        for (int rf = 0; rf < 4; ++rf)
            #pragma unroll
            for (int cf = 0; cf < 4; ++cf)
                #pragma unroll
                for (int r = 0; r < 4; ++r)
                    red[wave - 1][lane][(rf * 4 + cf) * 4 + r] = acc[rf][cf][r];
    }
    __syncthreads();
    if (wave != 0) return;

    #pragma unroll
    for (int rf = 0; rf < 4; ++rf)
        #pragma unroll
        for (int cf = 0; cf < 4; ++cf)
            #pragma unroll
            for (int r = 0; r < 4; ++r){
                int idx = (rf * 4 + cf) * 4 + r;
                acc[rf][cf][r] += red[0][lane][idx] + red[1][lane][idx] + red[2][lane][idx];
            }

    // scale + softmax over d (rows); column e lives in lanes {e, e+16, e+32, e+48}
    unsigned short* wout = wT + (long)bh * 4096;
    #pragma unroll
    for (int cf = 0; cf < 4; ++cf){
        float pv[16];
        float m = -3.4e38f;
        #pragma unroll
        for (int rf = 0; rf < 4; ++rf)
            #pragma unroll
            for (int r = 0; r < 4; ++r){
                float s = acc[rf][cf][r] * 0.125f;
                pv[rf * 4 + r] = s;
                m = fmaxf(m, s);
            }
        m = fmaxf(m, __shfl_xor(m, 16));
        m = fmaxf(m, __shfl_xor(m, 32));
        float sum = 0.f;
        #pragma unroll
        for (int k = 0; k < 16; ++k){ pv[k] = __expf(pv[k] - m); sum += pv[k]; }
        sum += __shfl_xor(sum, 16);
        sum += __shfl_xor(sum, 32);
        float inv = 1.f / sum;
        int e = cf * 16 + (lane & 15);
        #pragma unroll
        for (int rf = 0; rf < 4; ++rf)
            #pragma unroll
            for (int r = 0; r < 4; ++r){
                int d = rf * 16 + 4 * (lane >> 4) + r;
                wout[e * 64 + d] = f2h(pv[rf * 4 + r] * inv);
            }
    }
}

// =====================================================================
// K6: apply — o[src][b][n][h*64+e] = sum_d x[b][n][h*64+d] * w[b,h][e][d]
// =====================================================================
__global__ __launch_bounds__(256) void k_apply(
    const float* __restrict__ x1, const float* __restrict__ x2,
    const unsigned short* __restrict__ wT, float* __restrict__ out)
{
    __shared__ float ep[4][64][64];
    const int b = blockIdx.z;
    const int h = blockIdx.y >> 1;
    const int src = blockIdx.y & 1;
    const int lane = threadIdx.x & 63, wave = threadIdx.x >> 6;
    const int n0 = blockIdx.x * 256 + wave * 64;

    const float* x = (src ? x2 : x1) + (long)b * 4096 * 768;
    float* o = out + (long)src * 8 * 4096 * 768 + (long)b * 4096 * 768;

    const unsigned short* W = wT + (long)(b * 12 + h) * 4096;
    f16x8 bw[4][2];
    #pragma unroll
    for (int fe = 0; fe < 4; ++fe)
        #pragma unroll
        for (int ks = 0; ks < 2; ++ks)
            bw[fe][ks] = *(const f16x8*)(W + (fe * 16 + (lane & 15)) * 64 + ks * 32 + (lane >> 4) * 8);

    f32x4 acc[4][4];
    #pragma unroll
    for (int i = 0; i < 4; ++i)
        #pragma unroll
        for (int j = 0; j < 4; ++j) acc[i][j] = (f32x4){0.f, 0.f, 0.f, 0.f};

    #pragma unroll
    for (int rf = 0; rf < 4; ++rf){
        const int row = n0 + rf * 16 + (lane & 15);
        const float* xr = x + (long)row * 768 + h * 64 + (lane >> 4) * 8;
        f32x4 v0 = *(const f32x4*)(xr);
        f32x4 v1 = *(const f32x4*)(xr + 4);
        f32x4 v2 = *(const f32x4*)(xr + 32);
        f32x4 v3 = *(const f32x4*)(xr + 36);
        f16x8 a0, a1;
        #pragma unroll
        for (int t = 0; t < 4; ++t){
            a0[t]     = (_Float16)v0[t];
            a0[t + 4] = (_Float16)v1[t];
            a1[t]     = (_Float16)v2[t];
            a1[t + 4] = (_Float16)v3[t];
        }
        #pragma unroll
        for (int fe = 0; fe < 4; ++fe){
            acc[rf][fe] = __builtin_amdgcn_mfma_f32_16x16x32_f16(a0, bw[fe][0], acc[rf][fe], 0, 0, 0);
            acc[rf][fe] = __builtin_amdgcn_mfma_f32_16x16x32_f16(a1, bw[fe][1], acc[rf][fe], 0, 0, 0);
        }
    }

    // wave-local LDS restage for coalesced float4 stores
    #pragma unroll
    for (int rf = 0; rf < 4; ++rf)
        #pragma unroll
        for (int fe = 0; fe < 4; ++fe)
            #pragma unroll
            for (int r = 0; r < 4; ++r)
                ep[wave][rf * 16 + 4 * (lane >> 4) + r][fe * 16 + (lane & 15)] = acc[rf][fe][r];

    #pragma unroll
    for (int pass = 0; pass < 16; ++pass){
        int rr = pass * 4 + (lane >> 4);
        f32x4 v = *(const f32x4*)&ep[wave][rr][(lane & 15) * 4];
        *(f32x4*)&o[(long)(n0 + rr) * 768 + h * 64 + (lane & 15) * 4] = v;
    }
}

__global__ void k_sentinel(float* o){ o[0] = 1.0e9f; }

// =====================================================================
extern "C" void kernel_launch(void* const* d_in, const int* in_sizes, int n_in,
                              void* d_out, int out_size, void* d_ws, size_t ws_size,
                              hipStream_t stream)
{
    (void)in_sizes; (void)n_in; (void)out_size;
    const float* x1  = (const float*)d_in[0];
    const float* x2  = (const float*)d_in[1];
    const float* seg = (const float*)d_in[2];
    const float* Wkv = (const float*)d_in[3];

    char* Wb = (char*)d_ws;
    unsigned short* X    = (unsigned short*)(Wb);                 // 50,331,648
    unsigned short* WT   = (unsigned short*)(Wb + 50331648);      //  2,359,296
    unsigned short* TT   = (unsigned short*)(Wb + 52690944);      //  9,437,184
    unsigned short* wT   = (unsigned short*)(Wb + 62128128);      //    786,432
    unsigned short* Gp16 = (unsigned short*)(Wb + 62914560);      // 28,311,552
    const size_t need = 91226112;

    if (ws_size < need){
        k_sentinel<<<1, 1, 0, stream>>>((float*)d_out);
        return;
    }

    // K1: seg -> X (f16, transposed);  W_kv -> WT (f16, transposed)
    k_transpose_f16<<<dim3(12, 64, 8), 256, 0, stream>>>(
        seg, X, 4096, 768, (long)4096 * 768, (long)768 * 4096);
    k_transpose_f16<<<dim3(24, 12, 1), 256, 0, stream>>>(
        Wkv, WT, 768, 1536, 0, 0);

    // K2: Gram, symmetric pairs, split-K=3, XCD-affine, f16 partials, 8-wave
    k_gram<<<dim3(504), 512, 0, stream>>>(X, Gp16);

    // K4: TT = WvT ·bt· (sum of partials), 8-wave
    k_tt<<<dim3(288), 512, 0, stream>>>(WT, Gp16, TT);

    // K5: ctx + softmax -> wT
    k_ctx<<<dim3(96), 256, 0, stream>>>(WT, TT, wT);

    // K6: apply to both queries
    k_apply<<<dim3(16, 24, 8), 256, 0, stream>>>(x1, x2, wT, (float*)d_out);
}